// Round 1
// baseline (19447.267 us; speedup 1.0000x reference)
//
#include <hip/hip_runtime.h>

typedef unsigned int u32;
typedef unsigned short u16;
typedef _Float16 h2v __attribute__((ext_vector_type(2)));

#define DEVI static __device__ __forceinline__

DEVI u32 pack2f(float a, float b){ h2v h; h[0] = (_Float16)a; h[1] = (_Float16)b; return __builtin_bit_cast(u32, h); }
DEVI u16 f2h(float a){ _Float16 h = (_Float16)a; return __builtin_bit_cast(u16, h); }
DEVI float h2f(u16 a){ return (float)__builtin_bit_cast(_Float16, a); }

#if defined(__has_builtin)
#if __has_builtin(__builtin_amdgcn_fdot2)
#define HAVE_FDOT2 1
#endif
#endif

DEVI float dot2(u32 w, u32 x, float c){
#ifdef HAVE_FDOT2
  return __builtin_amdgcn_fdot2(__builtin_bit_cast(h2v, w), __builtin_bit_cast(h2v, x), c, false);
#else
  h2v a = __builtin_bit_cast(h2v, w), b = __builtin_bit_cast(h2v, x);
  c = fmaf((float)a[0], (float)b[0], c);
  return fmaf((float)a[1], (float)b[1], c);
#endif
}

DEVI float fsig(float x){ return 1.f / (1.f + __expf(-x)); }
DEVI float ftanh(float x){
  x = fminf(12.f, fmaxf(-12.f, x));
  float e = __expf(2.f * x);
  return (e - 1.f) / (e + 1.f);
}

// ---------------- weight repack kernels ----------------

// gru_Wih (3,2,1536,1024) f32 -> WgT[(l*512+kd)*3072 + (d*1536+g)]  f16 pair (k=2kd,2kd+1)
__global__ void k_pack_wih(const float* __restrict__ W, u32* __restrict__ out){
  int idx = blockIdx.x * 256 + threadIdx.x;   // 3*2*1536*512 = 4,718,592
  int kd = idx & 511;
  int q = idx >> 9;          // q = (l*2+d)*1536 + g
  int g = q % 1536;
  int ld = q / 1536;
  const float* src = W + (size_t)q * 1024 + kd * 2;
  int l = ld >> 1, d = ld & 1;
  int n = d * 1536 + g;
  out[(size_t)(l * 512 + kd) * 3072 + n] = pack2f(src[0], src[1]);
}

// gru_Whh (3,2,1536,512) f32 -> Wr[(((ld*16+w)*2+s)*128+kd)*96 + rr]  (rr = gate*32 + u%32, w = u/32)
__global__ void k_pack_whh(const float* __restrict__ W, u32* __restrict__ out){
  int idx = blockIdx.x * 256 + threadIdx.x;   // 3*2*1536*256 = 2,359,296
  int kp = idx & 255;
  int q = idx >> 8;          // (l*2+d)*1536 + g
  int g = q % 1536;
  int ld = q / 1536;
  const float* src = W + (size_t)q * 512 + kp * 2;
  int gate = g >> 9, u = g & 511;
  int w = u >> 5, uu = u & 31;
  int rr = gate * 32 + uu;
  int s = kp >> 7, kd = kp & 127;
  out[(size_t)(((ld * 16 + w) * 2 + s) * 128 + kd) * 96 + rr] = pack2f(src[0], src[1]);
}

// Wih1 (4,2,128,256) -> wp1[(j*128+kd)*256 + (d*128+i)] ; fc_W (61,1024) -> fcT[kd*64+o]
__global__ void k_pack_misc(const float* __restrict__ Wih1, const float* __restrict__ fcW,
                            u32* __restrict__ wp1, u32* __restrict__ fcT){
  int idx = blockIdx.x * 256 + threadIdx.x;
  if (idx < 131072){
    int c = idx & 255; int q = idx >> 8; int kd = q & 127; int j = q >> 7;
    int d = c >> 7, i = c & 127;
    const float* src = Wih1 + ((size_t)(j * 2 + d) * 128 + i) * 256 + kd * 2;
    wp1[idx] = pack2f(src[0], src[1]);
  } else if (idx < 131072 + 32768){
    int e = idx - 131072;
    int o = e & 63, kd = e >> 6;
    u32 v = 0;
    if (o < 61) v = pack2f(fcW[o * 1024 + kd * 2], fcW[o * 1024 + kd * 2 + 1]);
    fcT[e] = v;
  }
}

// ---------------- stage 1: per-frame biRNNs ----------------

// Layer-1 biRNN, gx fused (K=16). grid 256 = (j,d)<<5 | fblock ; block 256 (2 groups x 128 units)
__global__ __launch_bounds__(256) void k_rnn1(const float* __restrict__ batch,
    const float* __restrict__ Wih0, const float* __restrict__ Whh0,
    const float* __restrict__ bih0, const float* __restrict__ bhh0,
    u16* __restrict__ y1h){
  int bid = blockIdx.x;
  int jd = bid >> 5, fb = bid & 31;
  int j = jd >> 1, d = jd & 1;
  __shared__ float Wi[16][129];
  __shared__ float Wh[128][129];
  __shared__ float hA[8][128];
  __shared__ float hB[8][128];
  __shared__ float xf[8][3][16];
  int tid = threadIdx.x;
  for (int e = tid; e < 2048; e += 256){ int i = e >> 4, k = e & 15; Wi[k][i] = Wih0[(jd * 128 + i) * 16 + k]; }
  for (int e = tid; e < 16384; e += 256){ int i = e >> 7, k = e & 127; Wh[k][i] = Whh0[(jd * 128 + i) * 128 + k]; }
  int i = tid & 127, p = tid >> 7;
  float bias = bih0[jd * 128 + i] + bhh0[jd * 128 + i];
  __syncthreads();
  for (int g8 = 0; g8 < 8; ++g8){
    int f0 = fb * 64 + g8 * 8;
    for (int e = tid; e < 384; e += 256){
      int q = e / 48, r = e % 48, t = r >> 4, k = r & 15;
      int f = f0 + q, b = f >> 8, fr = f & 255;
      xf[q][t][k] = batch[((size_t)b * 768 + fr * 3 + t) * 64 + j * 16 + k];
    }
    __syncthreads();
    int q0 = p * 4;
    for (int tt = 0; tt < 3; ++tt){
      int ta = d ? 2 - tt : tt;
      float a0 = bias, a1 = bias, a2 = bias, a3 = bias;
      #pragma unroll
      for (int k = 0; k < 16; ++k){
        float w = Wi[k][i];
        a0 = fmaf(w, xf[q0 + 0][ta][k], a0);
        a1 = fmaf(w, xf[q0 + 1][ta][k], a1);
        a2 = fmaf(w, xf[q0 + 2][ta][k], a2);
        a3 = fmaf(w, xf[q0 + 3][ta][k], a3);
      }
      if (tt > 0){
        float (*hr)[128] = (tt == 1) ? hA : hB;
        #pragma unroll 4
        for (int k = 0; k < 128; ++k){
          float w = Wh[k][i];
          a0 = fmaf(w, hr[q0 + 0][k], a0);
          a1 = fmaf(w, hr[q0 + 1][k], a1);
          a2 = fmaf(w, hr[q0 + 2][k], a2);
          a3 = fmaf(w, hr[q0 + 3][k], a3);
        }
      }
      float h0 = ftanh(a0), h1 = ftanh(a1), hh2 = ftanh(a2), h3 = ftanh(a3);
      float (*hw)[128] = (tt & 1) ? hB : hA;
      hw[q0 + 0][i] = h0; hw[q0 + 1][i] = h1; hw[q0 + 2][i] = hh2; hw[q0 + 3][i] = h3;
      size_t obase = ((size_t)(j * 2048 + f0) * 3 + ta) * 256 + d * 128 + i;
      y1h[obase + (size_t)(q0 + 0) * 768] = f2h(h0);
      y1h[obase + (size_t)(q0 + 1) * 768] = f2h(h1);
      y1h[obase + (size_t)(q0 + 2) * 768] = f2h(hh2);
      y1h[obase + (size_t)(q0 + 3) * 768] = f2h(h3);
      __syncthreads();
    }
  }
}

// gx2 = y1 @ Wih1^T + bih1 + bhh1. grid (384 rowtiles, 4 j); block 256 (c = d*128+i)
__global__ __launch_bounds__(256) void k_gx2(const u16* __restrict__ y1h,
    const u32* __restrict__ Wp1, const float* __restrict__ bih1,
    const float* __restrict__ bhh1, u16* __restrict__ gx2h){
  int j = blockIdx.y;
  int rt0 = blockIdx.x * 16;
  __shared__ u32 yL[16][128];
  int tid = threadIdx.x;
  const u32* y1d = (const u32*)y1h;
  for (int e = tid; e < 2048; e += 256){
    int rr = e >> 7, kd = e & 127;
    yL[rr][kd] = y1d[(size_t)(j * 6144 + rt0 + rr) * 128 + kd];
  }
  __syncthreads();
  int c = tid, d = c >> 7, i = c & 127;
  float acc[16];
  #pragma unroll
  for (int rr = 0; rr < 16; ++rr) acc[rr] = 0.f;
  const u32* wp = Wp1 + (size_t)j * 128 * 256 + c;
  for (int kd = 0; kd < 128; ++kd){
    u32 w = wp[(size_t)kd * 256];
    #pragma unroll
    for (int rr = 0; rr < 16; ++rr) acc[rr] = dot2(w, yL[rr][kd], acc[rr]);
  }
  float bias = bih1[(j * 2 + d) * 128 + i] + bhh1[(j * 2 + d) * 128 + i];
  #pragma unroll
  for (int rr = 0; rr < 16; ++rr)
    gx2h[(size_t)(j * 6144 + rt0 + rr) * 256 + c] = f2h(acc[rr] + bias);
}

// Layer-2: fwd 3-step recurrence; bwd = tanh(gx2[t=2]) single step. grid 128 = j<<5|fb, block 256
__global__ __launch_bounds__(256) void k_rnn2(const u16* __restrict__ gx2h,
    const float* __restrict__ Whh1, u16* __restrict__ x0h){
  int bid = blockIdx.x;
  int j = bid >> 5, fb = bid & 31;
  __shared__ float Wh[128][129];
  __shared__ float hA[8][128];
  __shared__ float hB[8][128];
  int tid = threadIdx.x;
  for (int e = tid; e < 16384; e += 256){ int i = e >> 7, k = e & 127; Wh[k][i] = Whh1[((size_t)(j * 2) * 128 + i) * 128 + k]; }
  int i = tid & 127, p = tid >> 7, q0 = p * 4;
  __syncthreads();
  for (int g8 = 0; g8 < 8; ++g8){
    int f0 = fb * 64 + g8 * 8;
    for (int tt = 0; tt < 3; ++tt){
      float a0 = h2f(gx2h[(size_t)(j * 6144 + (f0 + q0 + 0) * 3 + tt) * 256 + i]);
      float a1 = h2f(gx2h[(size_t)(j * 6144 + (f0 + q0 + 1) * 3 + tt) * 256 + i]);
      float a2 = h2f(gx2h[(size_t)(j * 6144 + (f0 + q0 + 2) * 3 + tt) * 256 + i]);
      float a3 = h2f(gx2h[(size_t)(j * 6144 + (f0 + q0 + 3) * 3 + tt) * 256 + i]);
      if (tt > 0){
        float (*hr)[128] = (tt == 1) ? hA : hB;
        #pragma unroll 4
        for (int k = 0; k < 128; ++k){
          float w = Wh[k][i];
          a0 = fmaf(w, hr[q0 + 0][k], a0);
          a1 = fmaf(w, hr[q0 + 1][k], a1);
          a2 = fmaf(w, hr[q0 + 2][k], a2);
          a3 = fmaf(w, hr[q0 + 3][k], a3);
        }
      }
      float h0 = ftanh(a0), h1 = ftanh(a1), hh2 = ftanh(a2), h3 = ftanh(a3);
      float (*hw)[128] = (tt & 1) ? hB : hA;
      hw[q0 + 0][i] = h0; hw[q0 + 1][i] = h1; hw[q0 + 2][i] = hh2; hw[q0 + 3][i] = h3;
      if (tt == 2){
        #pragma unroll
        for (int qq = 0; qq < 4; ++qq){
          int f = f0 + q0 + qq;
          float hv = (qq == 0) ? h0 : (qq == 1) ? h1 : (qq == 2) ? hh2 : h3;
          x0h[(size_t)f * 1024 + j * 256 + i] = f2h(hv);
          float bv = ftanh(h2f(gx2h[(size_t)(j * 6144 + f * 3 + 2) * 256 + 128 + i]));
          x0h[(size_t)f * 1024 + j * 256 + 128 + i] = f2h(bv);
        }
      }
      __syncthreads();
    }
  }
}

// ---------------- GRU stack ----------------

// gx = x @ Wih^T + bih (+bhh for r,z). grid (12 ntiles, 128 = b<<4|ttile); block 256
__global__ __launch_bounds__(256) void k_gru_gx(int l, const u16* __restrict__ xin,
    const u32* __restrict__ WgT, const float* __restrict__ gbih,
    const float* __restrict__ gbhh, const int* __restrict__ lengths,
    u16* __restrict__ gxh){
  int b = blockIdx.y >> 4, t0 = (blockIdx.y & 15) * 16;
  int nf = lengths[b] / 3;
  if (t0 >= nf) return;
  __shared__ u32 xL[16][512];
  int tid = threadIdx.x;
  const u32* xd = (const u32*)xin;
  for (int e = tid; e < 8192; e += 256){
    int rr = e >> 9, kd = e & 511;
    xL[rr][kd] = xd[(size_t)(b * 256 + t0 + rr) * 512 + kd];
  }
  __syncthreads();
  int n = blockIdx.x * 256 + tid;
  int d = (n >= 1536) ? 1 : 0;
  int g = n - d * 1536;
  float acc[16];
  #pragma unroll
  for (int rr = 0; rr < 16; ++rr) acc[rr] = 0.f;
  const u32* wp = WgT + (size_t)l * 512 * 3072 + n;
  for (int kd = 0; kd < 512; ++kd){
    u32 w = wp[(size_t)kd * 3072];
    #pragma unroll
    for (int rr = 0; rr < 16; ++rr) acc[rr] = dot2(w, xL[rr][kd], acc[rr]);
  }
  int ld = l * 2 + d;
  float bias = gbih[ld * 1536 + g] + ((g < 1024) ? gbhh[ld * 1536 + g] : 0.f);
  #pragma unroll
  for (int rr = 0; rr < 16; ++rr)
    gxh[(size_t)((d * 8 + b) * 256 + t0 + rr) * 1536 + g] = f2h(acc[rr] + bias);
}

// GRU recurrence: 16 chains x 16 WGs (32 hidden units each), flag-synced each step.
// grid 256 = d<<7 | b<<4 | w ; block 256 = (s = tid>>7 k-half) x (rr = tid&127, rows 0..95 active)
__global__ __launch_bounds__(256, 1) void k_gru_rec(int l, const u16* __restrict__ gxh,
    const float* __restrict__ gbhh, const int* __restrict__ lengths,
    const u32* __restrict__ Wr, float* __restrict__ hbuf, int* __restrict__ cnt,
    u16* __restrict__ xout){
  int bid = blockIdx.x;
  int w = bid & 15, b = (bid >> 4) & 7, d = bid >> 7;
  int chain = d * 8 + b;
  int nf = lengths[b] / 3;
  int tid = threadIdx.x;
  int rr = tid & 127, s = tid >> 7;
  int u0 = w * 32;
  __shared__ u32 hL[256];
  __shared__ float red[96];
  __shared__ float dotv[96];
  float* hbL = hbuf + (size_t)l * (2 * 16 * 512);
  int* cp = cnt + l * 16 + chain;
  const u32* wp = Wr + (size_t)(((l * 2 + d) * 16 + w) * 2 + s) * 128 * 96 + ((rr < 96) ? rr : 95);
  const u16* gxb = gxh + (size_t)chain * 256 * 1536;
  float bhn = (tid < 32) ? gbhh[(l * 2 + d) * 1536 + 1024 + u0 + tid] : 0.f;
  for (int st = 0; st < nf; ++st){
    int t = d ? (nf - 1 - st) : st;
    int rp = st & 1;
    const float* hr = hbL + (size_t)(rp * 16 + chain) * 512;
    {
      float2 hv = *(const float2*)(hr + tid * 2);
      hL[tid] = pack2f(hv.x, hv.y);
    }
    __syncthreads();
    float acc = 0.f;
    #pragma unroll 8
    for (int kd = 0; kd < 128; ++kd){
      u32 wv = wp[kd * 96];
      u32 hv = hL[s * 128 + kd];
      acc = dot2(wv, hv, acc);
    }
    if (s == 1 && rr < 96) red[rr] = acc;
    __syncthreads();
    if (s == 0 && rr < 96) dotv[rr] = acc + red[rr];
    __syncthreads();
    if (tid < 32){
      int u = tid;
      const u16* gxr = gxb + (size_t)t * 1536;
      float rg = fsig(dotv[u] + h2f(gxr[u0 + u]));
      float zg = fsig(dotv[32 + u] + h2f(gxr[512 + u0 + u]));
      float ng = ftanh(h2f(gxr[1024 + u0 + u]) + rg * (dotv[64 + u] + bhn));
      float hold = hr[u0 + u];
      float hnew = (1.f - zg) * ng + zg * hold;
      hbL[(size_t)((rp ^ 1) * 16 + chain) * 512 + u0 + u] = hnew;
      xout[(size_t)(b * 256 + t) * 1024 + d * 512 + u0 + u] = f2h(hnew);
    }
    __threadfence();
    __syncthreads();
    if (tid == 0){
      __hip_atomic_fetch_add(cp, 1, __ATOMIC_RELEASE, __HIP_MEMORY_SCOPE_AGENT);
      int target = 16 * (st + 1);
      int guard = 0;
      while (__hip_atomic_load(cp, __ATOMIC_ACQUIRE, __HIP_MEMORY_SCOPE_AGENT) < target){
        __builtin_amdgcn_s_sleep(2);
        if (++guard > (1 << 25)) break;
      }
    }
    __syncthreads();
  }
}

// FC + packed gather. grid 256 = b<<5 | ttile ; block 256 = (ks = tid>>6) x (o = tid&63)
__global__ __launch_bounds__(256) void k_fc(const u16* __restrict__ x2h,
    const u32* __restrict__ fcT, const float* __restrict__ fcb,
    const int* __restrict__ lengths, float* __restrict__ out){
  int bid = blockIdx.x;
  int b = bid >> 5, t0 = (bid & 31) * 8;
  int nf = lengths[b] / 3;
  if (t0 >= nf) return;
  int off = 0;
  for (int b2 = 0; b2 < b; ++b2) off += lengths[b2] / 3;
  __shared__ u32 xL[512];
  __shared__ float redf[4][64];
  int tid = threadIdx.x;
  int o = tid & 63, ks = tid >> 6;
  const u32* xd = (const u32*)x2h;
  int tend = (t0 + 8 < nf) ? (t0 + 8) : nf;
  for (int t = t0; t < tend; ++t){
    for (int e = tid; e < 512; e += 256) xL[e] = xd[(size_t)(b * 256 + t) * 512 + e];
    __syncthreads();
    float acc = 0.f;
    const u32* fp = fcT + ks * 128 * 64 + o;
    #pragma unroll 4
    for (int kd = 0; kd < 128; ++kd)
      acc = dot2(fp[kd * 64], xL[ks * 128 + kd], acc);
    redf[ks][o] = acc;
    __syncthreads();
    if (ks == 0 && o < 61)
      out[(size_t)(off + t) * 61 + o] = redf[0][o] + redf[1][o] + redf[2][o] + redf[3][o] + fcb[o];
    __syncthreads();
  }
}

// ---------------- host ----------------

static constexpr size_t alignup(size_t x){ return (x + 255) & ~(size_t)255; }

extern "C" void kernel_launch(void* const* d_in, const int* in_sizes, int n_in,
                              void* d_out, int out_size, void* d_ws, size_t ws_size,
                              hipStream_t stream){
  const float* batch = (const float*)d_in[0];
  const int* lengths = (const int*)d_in[1];
  const float* Wih0 = (const float*)d_in[2];
  const float* Whh0 = (const float*)d_in[3];
  const float* bih0 = (const float*)d_in[4];
  const float* bhh0 = (const float*)d_in[5];
  const float* Wih1 = (const float*)d_in[6];
  const float* Whh1 = (const float*)d_in[7];
  const float* bih1 = (const float*)d_in[8];
  const float* bhh1 = (const float*)d_in[9];
  const float* gWih = (const float*)d_in[10];
  const float* gWhh = (const float*)d_in[11];
  const float* gbih = (const float*)d_in[12];
  const float* gbhh = (const float*)d_in[13];
  const float* fcW  = (const float*)d_in[14];
  const float* fcb  = (const float*)d_in[15];

  char* ws = (char*)d_ws;
  size_t off = 0;
  const size_t O_CNT  = off; off = alignup(off + 3 * 16 * 4);
  const size_t O_HBUF = off; off = alignup(off + (size_t)3 * 2 * 16 * 512 * 4);
  const size_t SYNC_BYTES = off;                       // zero [0, off) every launch
  const size_t O_Y1H  = off; off = alignup(off + (size_t)4 * 2048 * 3 * 256 * 2);
  const size_t O_GX2H = off; off = alignup(off + (size_t)4 * 2048 * 3 * 256 * 2);
  const size_t O_X0   = off; off = alignup(off + (size_t)8 * 256 * 1024 * 2);
  const size_t O_X1   = off; off = alignup(off + (size_t)8 * 256 * 1024 * 2);
  const size_t O_X2   = off; off = alignup(off + (size_t)8 * 256 * 1024 * 2);
  const size_t O_GXH  = off; off = alignup(off + (size_t)2 * 8 * 256 * 1536 * 2);
  const size_t O_WGT  = off; off = alignup(off + (size_t)3 * 512 * 3072 * 4);
  const size_t O_WRH  = off; off = alignup(off + (size_t)3 * 2 * 16 * 2 * 128 * 96 * 4);
  const size_t O_WP1  = off; off = alignup(off + (size_t)4 * 128 * 256 * 4);
  const size_t O_FCT  = off; off = alignup(off + (size_t)512 * 64 * 4);
  (void)ws_size; (void)in_sizes; (void)n_in; (void)out_size;

  int*  CNT  = (int*)(ws + O_CNT);
  float* HBUF = (float*)(ws + O_HBUF);
  u16* Y1H  = (u16*)(ws + O_Y1H);
  u16* GX2H = (u16*)(ws + O_GX2H);
  u16* X0   = (u16*)(ws + O_X0);
  u16* X1   = (u16*)(ws + O_X1);
  u16* X2   = (u16*)(ws + O_X2);
  u16* GXH  = (u16*)(ws + O_GXH);
  u32* WGT  = (u32*)(ws + O_WGT);
  u32* WRH  = (u32*)(ws + O_WRH);
  u32* WP1  = (u32*)(ws + O_WP1);
  u32* FCT  = (u32*)(ws + O_FCT);

  hipMemsetAsync(ws, 0, SYNC_BYTES, stream);

  k_pack_wih <<<18432, 256, 0, stream>>>(gWih, WGT);
  k_pack_whh <<<9216, 256, 0, stream>>>(gWhh, WRH);
  k_pack_misc<<<640, 256, 0, stream>>>(Wih1, fcW, WP1, FCT);

  k_rnn1<<<256, 256, 0, stream>>>(batch, Wih0, Whh0, bih0, bhh0, Y1H);
  k_gx2 <<<dim3(384, 4), 256, 0, stream>>>(Y1H, WP1, bih1, bhh1, GX2H);
  k_rnn2<<<128, 256, 0, stream>>>(GX2H, Whh1, X0);

  u16* X[3] = { X0, X1, X2 };
  for (int l = 0; l < 3; ++l){
    u16* xin = X[l];
    u16* xout = X[(l + 1) % 3];
    k_gru_gx <<<dim3(12, 128), 256, 0, stream>>>(l, xin, WGT, gbih, gbhh, lengths, GXH);
    k_gru_rec<<<256, 256, 0, stream>>>(l, GXH, gbhh, lengths, WRH, HBUF, CNT, xout);
  }
  k_fc<<<256, 256, 0, stream>>>(X[0], FCT, fcb, lengths, (float*)d_out);
}

// Round 2
// 3401.129 us; speedup vs baseline: 5.7179x; 5.7179x over previous
//
#include <hip/hip_runtime.h>

typedef unsigned int u32;
typedef unsigned short u16;
typedef _Float16 h2v __attribute__((ext_vector_type(2)));

#define DEVI static __device__ __forceinline__

DEVI u32 pack2f(float a, float b){ h2v h; h[0] = (_Float16)a; h[1] = (_Float16)b; return __builtin_bit_cast(u32, h); }
DEVI u16 f2h(float a){ _Float16 h = (_Float16)a; return __builtin_bit_cast(u16, h); }
DEVI float h2f(u16 a){ return (float)__builtin_bit_cast(_Float16, a); }

#if defined(__has_builtin)
#if __has_builtin(__builtin_amdgcn_fdot2)
#define HAVE_FDOT2 1
#endif
#endif

DEVI float dot2(u32 w, u32 x, float c){
#ifdef HAVE_FDOT2
  return __builtin_amdgcn_fdot2(__builtin_bit_cast(h2v, w), __builtin_bit_cast(h2v, x), c, false);
#else
  h2v a = __builtin_bit_cast(h2v, w), b = __builtin_bit_cast(h2v, x);
  c = fmaf((float)a[0], (float)b[0], c);
  return fmaf((float)a[1], (float)b[1], c);
#endif
}

DEVI float fsig(float x){ return 1.f / (1.f + __expf(-x)); }
DEVI float ftanh(float x){
  x = fminf(12.f, fmaxf(-12.f, x));
  float e = __expf(2.f * x);
  return (e - 1.f) / (e + 1.f);
}

// ---------------- weight repack kernels ----------------

// gru_Wih (3,2,1536,1024) f32 -> WgT[(l*512+kd)*3072 + (d*1536+g)]  f16 pair (k=2kd,2kd+1)
__global__ void k_pack_wih(const float* __restrict__ W, u32* __restrict__ out){
  int idx = blockIdx.x * 256 + threadIdx.x;   // 3*2*1536*512 = 4,718,592
  int kd = idx & 511;
  int q = idx >> 9;          // q = (l*2+d)*1536 + g
  int g = q % 1536;
  int ld = q / 1536;
  const float* src = W + (size_t)q * 1024 + kd * 2;
  int l = ld >> 1, d = ld & 1;
  int n = d * 1536 + g;
  out[(size_t)(l * 512 + kd) * 3072 + n] = pack2f(src[0], src[1]);
}

// gru_Whh (3,2,1536,512) f32 -> Wr[(((ld*16+w)*2+s)*128+kd)*96 + rr]  (rr = gate*32 + u%32, w = u/32)
__global__ void k_pack_whh(const float* __restrict__ W, u32* __restrict__ out){
  int idx = blockIdx.x * 256 + threadIdx.x;   // 3*2*1536*256 = 2,359,296
  int kp = idx & 255;
  int q = idx >> 8;          // (l*2+d)*1536 + g
  int g = q % 1536;
  int ld = q / 1536;
  const float* src = W + (size_t)q * 512 + kp * 2;
  int gate = g >> 9, u = g & 511;
  int w = u >> 5, uu = u & 31;
  int rr = gate * 32 + uu;
  int s = kp >> 7, kd = kp & 127;
  out[(size_t)(((ld * 16 + w) * 2 + s) * 128 + kd) * 96 + rr] = pack2f(src[0], src[1]);
}

// Wih1 (4,2,128,256) -> wp1[(j*128+kd)*256 + (d*128+i)] ; fc_W (61,1024) -> fcT[kd*64+o]
__global__ void k_pack_misc(const float* __restrict__ Wih1, const float* __restrict__ fcW,
                            u32* __restrict__ wp1, u32* __restrict__ fcT){
  int idx = blockIdx.x * 256 + threadIdx.x;
  if (idx < 131072){
    int c = idx & 255; int q = idx >> 8; int kd = q & 127; int j = q >> 7;
    int d = c >> 7, i = c & 127;
    const float* src = Wih1 + ((size_t)(j * 2 + d) * 128 + i) * 256 + kd * 2;
    wp1[idx] = pack2f(src[0], src[1]);
  } else if (idx < 131072 + 32768){
    int e = idx - 131072;
    int o = e & 63, kd = e >> 6;
    u32 v = 0;
    if (o < 61) v = pack2f(fcW[o * 1024 + kd * 2], fcW[o * 1024 + kd * 2 + 1]);
    fcT[e] = v;
  }
}

// ---------------- stage 1: per-frame biRNNs ----------------

// Layer-1 biRNN, gx fused (K=16). grid 256 = (j,d)<<5 | fblock ; block 256 (2 groups x 128 units)
__global__ __launch_bounds__(256) void k_rnn1(const float* __restrict__ batch,
    const float* __restrict__ Wih0, const float* __restrict__ Whh0,
    const float* __restrict__ bih0, const float* __restrict__ bhh0,
    u16* __restrict__ y1h){
  int bid = blockIdx.x;
  int jd = bid >> 5, fb = bid & 31;
  int j = jd >> 1, d = jd & 1;
  __shared__ float Wi[16][129];
  __shared__ float Wh[128][129];
  __shared__ float hA[8][128];
  __shared__ float hB[8][128];
  __shared__ float xf[8][3][16];
  int tid = threadIdx.x;
  for (int e = tid; e < 2048; e += 256){ int i = e >> 4, k = e & 15; Wi[k][i] = Wih0[(jd * 128 + i) * 16 + k]; }
  for (int e = tid; e < 16384; e += 256){ int i = e >> 7, k = e & 127; Wh[k][i] = Whh0[(jd * 128 + i) * 128 + k]; }
  int i = tid & 127, p = tid >> 7;
  float bias = bih0[jd * 128 + i] + bhh0[jd * 128 + i];
  __syncthreads();
  for (int g8 = 0; g8 < 8; ++g8){
    int f0 = fb * 64 + g8 * 8;
    for (int e = tid; e < 384; e += 256){
      int q = e / 48, r = e % 48, t = r >> 4, k = r & 15;
      int f = f0 + q, b = f >> 8, fr = f & 255;
      xf[q][t][k] = batch[((size_t)b * 768 + fr * 3 + t) * 64 + j * 16 + k];
    }
    __syncthreads();
    int q0 = p * 4;
    for (int tt = 0; tt < 3; ++tt){
      int ta = d ? 2 - tt : tt;
      float a0 = bias, a1 = bias, a2 = bias, a3 = bias;
      #pragma unroll
      for (int k = 0; k < 16; ++k){
        float w = Wi[k][i];
        a0 = fmaf(w, xf[q0 + 0][ta][k], a0);
        a1 = fmaf(w, xf[q0 + 1][ta][k], a1);
        a2 = fmaf(w, xf[q0 + 2][ta][k], a2);
        a3 = fmaf(w, xf[q0 + 3][ta][k], a3);
      }
      if (tt > 0){
        float (*hr)[128] = (tt == 1) ? hA : hB;
        #pragma unroll 4
        for (int k = 0; k < 128; ++k){
          float w = Wh[k][i];
          a0 = fmaf(w, hr[q0 + 0][k], a0);
          a1 = fmaf(w, hr[q0 + 1][k], a1);
          a2 = fmaf(w, hr[q0 + 2][k], a2);
          a3 = fmaf(w, hr[q0 + 3][k], a3);
        }
      }
      float h0 = ftanh(a0), h1 = ftanh(a1), hh2 = ftanh(a2), h3 = ftanh(a3);
      float (*hw)[128] = (tt & 1) ? hB : hA;
      hw[q0 + 0][i] = h0; hw[q0 + 1][i] = h1; hw[q0 + 2][i] = hh2; hw[q0 + 3][i] = h3;
      size_t obase = ((size_t)(j * 2048 + f0) * 3 + ta) * 256 + d * 128 + i;
      y1h[obase + (size_t)(q0 + 0) * 768] = f2h(h0);
      y1h[obase + (size_t)(q0 + 1) * 768] = f2h(h1);
      y1h[obase + (size_t)(q0 + 2) * 768] = f2h(hh2);
      y1h[obase + (size_t)(q0 + 3) * 768] = f2h(h3);
      __syncthreads();
    }
  }
}

// gx2 = y1 @ Wih1^T + bih1 + bhh1. grid (384 rowtiles, 4 j); block 256 (c = d*128+i)
__global__ __launch_bounds__(256) void k_gx2(const u16* __restrict__ y1h,
    const u32* __restrict__ Wp1, const float* __restrict__ bih1,
    const float* __restrict__ bhh1, u16* __restrict__ gx2h){
  int j = blockIdx.y;
  int rt0 = blockIdx.x * 16;
  __shared__ u32 yL[16][128];
  int tid = threadIdx.x;
  const u32* y1d = (const u32*)y1h;
  for (int e = tid; e < 2048; e += 256){
    int rr = e >> 7, kd = e & 127;
    yL[rr][kd] = y1d[(size_t)(j * 6144 + rt0 + rr) * 128 + kd];
  }
  __syncthreads();
  int c = tid, d = c >> 7, i = c & 127;
  float acc[16];
  #pragma unroll
  for (int rr = 0; rr < 16; ++rr) acc[rr] = 0.f;
  const u32* wp = Wp1 + (size_t)j * 128 * 256 + c;
  for (int kd = 0; kd < 128; ++kd){
    u32 w = wp[(size_t)kd * 256];
    #pragma unroll
    for (int rr = 0; rr < 16; ++rr) acc[rr] = dot2(w, yL[rr][kd], acc[rr]);
  }
  float bias = bih1[(j * 2 + d) * 128 + i] + bhh1[(j * 2 + d) * 128 + i];
  #pragma unroll
  for (int rr = 0; rr < 16; ++rr)
    gx2h[(size_t)(j * 6144 + rt0 + rr) * 256 + c] = f2h(acc[rr] + bias);
}

// Layer-2: fwd 3-step recurrence; bwd = tanh(gx2[t=2]) single step. grid 128 = j<<5|fb, block 256
__global__ __launch_bounds__(256) void k_rnn2(const u16* __restrict__ gx2h,
    const float* __restrict__ Whh1, u16* __restrict__ x0h){
  int bid = blockIdx.x;
  int j = bid >> 5, fb = bid & 31;
  __shared__ float Wh[128][129];
  __shared__ float hA[8][128];
  __shared__ float hB[8][128];
  int tid = threadIdx.x;
  for (int e = tid; e < 16384; e += 256){ int i = e >> 7, k = e & 127; Wh[k][i] = Whh1[((size_t)(j * 2) * 128 + i) * 128 + k]; }
  int i = tid & 127, p = tid >> 7, q0 = p * 4;
  __syncthreads();
  for (int g8 = 0; g8 < 8; ++g8){
    int f0 = fb * 64 + g8 * 8;
    for (int tt = 0; tt < 3; ++tt){
      float a0 = h2f(gx2h[(size_t)(j * 6144 + (f0 + q0 + 0) * 3 + tt) * 256 + i]);
      float a1 = h2f(gx2h[(size_t)(j * 6144 + (f0 + q0 + 1) * 3 + tt) * 256 + i]);
      float a2 = h2f(gx2h[(size_t)(j * 6144 + (f0 + q0 + 2) * 3 + tt) * 256 + i]);
      float a3 = h2f(gx2h[(size_t)(j * 6144 + (f0 + q0 + 3) * 3 + tt) * 256 + i]);
      if (tt > 0){
        float (*hr)[128] = (tt == 1) ? hA : hB;
        #pragma unroll 4
        for (int k = 0; k < 128; ++k){
          float w = Wh[k][i];
          a0 = fmaf(w, hr[q0 + 0][k], a0);
          a1 = fmaf(w, hr[q0 + 1][k], a1);
          a2 = fmaf(w, hr[q0 + 2][k], a2);
          a3 = fmaf(w, hr[q0 + 3][k], a3);
        }
      }
      float h0 = ftanh(a0), h1 = ftanh(a1), hh2 = ftanh(a2), h3 = ftanh(a3);
      float (*hw)[128] = (tt & 1) ? hB : hA;
      hw[q0 + 0][i] = h0; hw[q0 + 1][i] = h1; hw[q0 + 2][i] = hh2; hw[q0 + 3][i] = h3;
      if (tt == 2){
        #pragma unroll
        for (int qq = 0; qq < 4; ++qq){
          int f = f0 + q0 + qq;
          float hv = (qq == 0) ? h0 : (qq == 1) ? h1 : (qq == 2) ? hh2 : h3;
          x0h[(size_t)f * 1024 + j * 256 + i] = f2h(hv);
          float bv = ftanh(h2f(gx2h[(size_t)(j * 6144 + f * 3 + 2) * 256 + 128 + i]));
          x0h[(size_t)f * 1024 + j * 256 + 128 + i] = f2h(bv);
        }
      }
      __syncthreads();
    }
  }
}

// ---------------- GRU stack ----------------

// gx = x @ Wih^T + bih (+bhh for r,z). grid (12 ntiles, 128 = b<<4|ttile); block 256
__global__ __launch_bounds__(256) void k_gru_gx(int l, const u16* __restrict__ xin,
    const u32* __restrict__ WgT, const float* __restrict__ gbih,
    const float* __restrict__ gbhh, const int* __restrict__ lengths,
    u16* __restrict__ gxh){
  int b = blockIdx.y >> 4, t0 = (blockIdx.y & 15) * 16;
  int nf = lengths[b] / 3;
  if (t0 >= nf) return;
  __shared__ u32 xL[16][512];
  int tid = threadIdx.x;
  const u32* xd = (const u32*)xin;
  for (int e = tid; e < 8192; e += 256){
    int rr = e >> 9, kd = e & 511;
    xL[rr][kd] = xd[(size_t)(b * 256 + t0 + rr) * 512 + kd];
  }
  __syncthreads();
  int n = blockIdx.x * 256 + tid;
  int d = (n >= 1536) ? 1 : 0;
  int g = n - d * 1536;
  float acc[16];
  #pragma unroll
  for (int rr = 0; rr < 16; ++rr) acc[rr] = 0.f;
  const u32* wp = WgT + (size_t)l * 512 * 3072 + n;
  for (int kd = 0; kd < 512; ++kd){
    u32 w = wp[(size_t)kd * 3072];
    #pragma unroll
    for (int rr = 0; rr < 16; ++rr) acc[rr] = dot2(w, xL[rr][kd], acc[rr]);
  }
  int ld = l * 2 + d;
  float bias = gbih[ld * 1536 + g] + ((g < 1024) ? gbhh[ld * 1536 + g] : 0.f);
  #pragma unroll
  for (int rr = 0; rr < 16; ++rr)
    gxh[(size_t)((d * 8 + b) * 256 + t0 + rr) * 1536 + g] = f2h(acc[rr] + bias);
}

// GRU recurrence v2: weights resident in LDS; fence-free relaxed-atomic sync.
// grid 256 = d<<7 | b<<4 | w ; block 256 = (s = tid>>7 k-half) x (rr = tid&127, rows 0..95 active)
__global__ __launch_bounds__(256, 1) void k_gru_rec(int l, const u16* __restrict__ gxh,
    const float* __restrict__ gbhh, const int* __restrict__ lengths,
    const u32* __restrict__ Wr, u32* __restrict__ hpk, int* __restrict__ flg,
    u16* __restrict__ xout){
  int bid = blockIdx.x;
  int w = bid & 15, b = (bid >> 4) & 7, d = bid >> 7;
  int chain = d * 8 + b;
  int nf = lengths[b] / 3;
  int tid = threadIdx.x;
  int rr = tid & 127, s = tid >> 7;
  int u0 = w * 32;
  __shared__ u32 WL[24576];        // 96 KB: [s][kd][rr], rr-major => conflict-free ds_read_b32
  __shared__ u32 hL[256];
  __shared__ float red[96];
  __shared__ float dotv[96];
  // stage this WG's 96x512 f16 weight slice into LDS once (contiguous copy)
  const u32* wsrc = Wr + (size_t)((l * 2 + d) * 16 + w) * 24576;
  for (int e = tid; e < 24576; e += 256) WL[e] = wsrc[e];
  u32* hp = hpk + (size_t)l * 8192 + chain * 256;      // [slot2][chain16][256] per layer
  int* fl = flg + (l * 16 + chain) * 16;
  const u16* gxb = gxh + (size_t)chain * 256 * 1536;
  float bhn = (tid < 32) ? gbhh[(l * 2 + d) * 1536 + 1024 + u0 + tid] : 0.f;
  int act = (rr < 96);
  const u32* wl = WL + s * 12288 + (act ? rr : 95);
  float hprev = 0.f;               // this lane's own unit state, exact f32 across steps
  __syncthreads();
  for (int st = 0; st < nf; ++st){
    int t = d ? (nf - 1 - st) : st;
    // prefetch this step's gx (independent of the sync) to hide load latency
    float gr = 0.f, gz = 0.f, gn = 0.f;
    if (tid < 32){
      const u16* gxr = gxb + (size_t)t * 1536 + u0 + tid;
      gr = h2f(gxr[0]); gz = h2f(gxr[512]); gn = h2f(gxr[1024]);
    }
    if (st > 0){
      if (tid < 16){
        int gd = 0;
        while (__hip_atomic_load(&fl[tid], __ATOMIC_RELAXED, __HIP_MEMORY_SCOPE_AGENT) < st){
          __builtin_amdgcn_s_sleep(1);
          if (++gd > (1 << 24)) break;   // fail-safe against hang
        }
      }
      __syncthreads();
    }
    // read full h_st (packed f16 pairs) via coherent relaxed atomics (no cache invalidates)
    hL[tid] = __hip_atomic_load(&hp[(st & 1) * 4096 + tid], __ATOMIC_RELAXED, __HIP_MEMORY_SCOPE_AGENT);
    __syncthreads();
    float acc = 0.f;
    #pragma unroll 16
    for (int kd = 0; kd < 128; ++kd)
      acc = dot2(wl[kd * 96], hL[s * 128 + kd], acc);
    if (s == 1 && act) red[rr] = acc;
    __syncthreads();
    if (s == 0 && act) dotv[rr] = acc + red[rr];
    __syncthreads();
    float hnew = 0.f;
    if (tid < 32){
      float rg = fsig(dotv[tid] + gr);
      float zg = fsig(dotv[32 + tid] + gz);
      float ng = ftanh(gn + rg * (dotv[64 + tid] + bhn));
      hnew = (1.f - zg) * ng + zg * hprev;
      hprev = hnew;
      xout[(size_t)(b * 256 + t) * 1024 + d * 512 + u0 + tid] = f2h(hnew);
    }
    // pack pairs in wave 0 and publish h_{st+1}
    float ha = __shfl(hnew, (tid & 15) * 2);
    float hb = __shfl(hnew, (tid & 15) * 2 + 1);
    if (tid < 16)
      __hip_atomic_store(&hp[((st + 1) & 1) * 4096 + (u0 >> 1) + tid], pack2f(ha, hb),
                         __ATOMIC_RELAXED, __HIP_MEMORY_SCOPE_AGENT);
    // hand-rolled release: drain wave-0 stores to the coherence point, then flag
    asm volatile("s_waitcnt vmcnt(0)" ::: "memory");
    if (tid == 0)
      __hip_atomic_store(&fl[w], st + 1, __ATOMIC_RELAXED, __HIP_MEMORY_SCOPE_AGENT);
    __syncthreads();
  }
}

// FC + packed gather. grid 256 = b<<5 | ttile ; block 256 = (ks = tid>>6) x (o = tid&63)
__global__ __launch_bounds__(256) void k_fc(const u16* __restrict__ x2h,
    const u32* __restrict__ fcT, const float* __restrict__ fcb,
    const int* __restrict__ lengths, float* __restrict__ out){
  int bid = blockIdx.x;
  int b = bid >> 5, t0 = (bid & 31) * 8;
  int nf = lengths[b] / 3;
  if (t0 >= nf) return;
  int off = 0;
  for (int b2 = 0; b2 < b; ++b2) off += lengths[b2] / 3;
  __shared__ u32 xL[512];
  __shared__ float redf[4][64];
  int tid = threadIdx.x;
  int o = tid & 63, ks = tid >> 6;
  const u32* xd = (const u32*)x2h;
  int tend = (t0 + 8 < nf) ? (t0 + 8) : nf;
  for (int t = t0; t < tend; ++t){
    for (int e = tid; e < 512; e += 256) xL[e] = xd[(size_t)(b * 256 + t) * 512 + e];
    __syncthreads();
    float acc = 0.f;
    const u32* fp = fcT + ks * 128 * 64 + o;
    #pragma unroll 4
    for (int kd = 0; kd < 128; ++kd)
      acc = dot2(fp[kd * 64], xL[ks * 128 + kd], acc);
    redf[ks][o] = acc;
    __syncthreads();
    if (ks == 0 && o < 61)
      out[(size_t)(off + t) * 61 + o] = redf[0][o] + redf[1][o] + redf[2][o] + redf[3][o] + fcb[o];
    __syncthreads();
  }
}

// ---------------- host ----------------

static constexpr size_t alignup(size_t x){ return (x + 255) & ~(size_t)255; }

extern "C" void kernel_launch(void* const* d_in, const int* in_sizes, int n_in,
                              void* d_out, int out_size, void* d_ws, size_t ws_size,
                              hipStream_t stream){
  const float* batch = (const float*)d_in[0];
  const int* lengths = (const int*)d_in[1];
  const float* Wih0 = (const float*)d_in[2];
  const float* Whh0 = (const float*)d_in[3];
  const float* bih0 = (const float*)d_in[4];
  const float* bhh0 = (const float*)d_in[5];
  const float* Wih1 = (const float*)d_in[6];
  const float* Whh1 = (const float*)d_in[7];
  const float* bih1 = (const float*)d_in[8];
  const float* bhh1 = (const float*)d_in[9];
  const float* gWih = (const float*)d_in[10];
  const float* gWhh = (const float*)d_in[11];
  const float* gbih = (const float*)d_in[12];
  const float* gbhh = (const float*)d_in[13];
  const float* fcW  = (const float*)d_in[14];
  const float* fcb  = (const float*)d_in[15];

  char* ws = (char*)d_ws;
  size_t off = 0;
  const size_t O_FLG  = off; off = alignup(off + (size_t)3 * 16 * 16 * 4);
  const size_t O_HPK  = off; off = alignup(off + (size_t)3 * 2 * 16 * 256 * 4);
  const size_t SYNC_BYTES = off;                       // zero [0, off) every launch
  const size_t O_Y1H  = off; off = alignup(off + (size_t)4 * 2048 * 3 * 256 * 2);
  const size_t O_GX2H = off; off = alignup(off + (size_t)4 * 2048 * 3 * 256 * 2);
  const size_t O_X0   = off; off = alignup(off + (size_t)8 * 256 * 1024 * 2);
  const size_t O_X1   = off; off = alignup(off + (size_t)8 * 256 * 1024 * 2);
  const size_t O_X2   = off; off = alignup(off + (size_t)8 * 256 * 1024 * 2);
  const size_t O_GXH  = off; off = alignup(off + (size_t)2 * 8 * 256 * 1536 * 2);
  const size_t O_WGT  = off; off = alignup(off + (size_t)3 * 512 * 3072 * 4);
  const size_t O_WRH  = off; off = alignup(off + (size_t)3 * 2 * 16 * 2 * 128 * 96 * 4);
  const size_t O_WP1  = off; off = alignup(off + (size_t)4 * 128 * 256 * 4);
  const size_t O_FCT  = off; off = alignup(off + (size_t)512 * 64 * 4);
  (void)ws_size; (void)in_sizes; (void)n_in; (void)out_size;

  int*  FLG  = (int*)(ws + O_FLG);
  u32* HPK  = (u32*)(ws + O_HPK);
  u16* Y1H  = (u16*)(ws + O_Y1H);
  u16* GX2H = (u16*)(ws + O_GX2H);
  u16* X0   = (u16*)(ws + O_X0);
  u16* X1   = (u16*)(ws + O_X1);
  u16* X2   = (u16*)(ws + O_X2);
  u16* GXH  = (u16*)(ws + O_GXH);
  u32* WGT  = (u32*)(ws + O_WGT);
  u32* WRH  = (u32*)(ws + O_WRH);
  u32* WP1  = (u32*)(ws + O_WP1);
  u32* FCT  = (u32*)(ws + O_FCT);

  hipMemsetAsync(ws, 0, SYNC_BYTES, stream);

  k_pack_wih <<<18432, 256, 0, stream>>>(gWih, WGT);
  k_pack_whh <<<9216, 256, 0, stream>>>(gWhh, WRH);
  k_pack_misc<<<640, 256, 0, stream>>>(Wih1, fcW, WP1, FCT);

  k_rnn1<<<256, 256, 0, stream>>>(batch, Wih0, Whh0, bih0, bhh0, Y1H);
  k_gx2 <<<dim3(384, 4), 256, 0, stream>>>(Y1H, WP1, bih1, bhh1, GX2H);
  k_rnn2<<<128, 256, 0, stream>>>(GX2H, Whh1, X0);

  u16* X[3] = { X0, X1, X2 };
  for (int l = 0; l < 3; ++l){
    u16* xin = X[l];
    u16* xout = X[(l + 1) % 3];
    k_gru_gx <<<dim3(12, 128), 256, 0, stream>>>(l, xin, WGT, gbih, gbhh, lengths, GXH);
    k_gru_rec<<<256, 256, 0, stream>>>(l, GXH, gbhh, lengths, WRH, HPK, FLG, xout);
  }
  k_fc<<<256, 256, 0, stream>>>(X[0], FCT, fcb, lengths, (float*)d_out);
}

// Round 3
// 2909.972 us; speedup vs baseline: 6.6830x; 1.1688x over previous
//
#include <hip/hip_runtime.h>

typedef unsigned int u32;
typedef unsigned short u16;
typedef unsigned long long u64;
typedef _Float16 h2v __attribute__((ext_vector_type(2)));

#define DEVI static __device__ __forceinline__

DEVI u32 pack2f(float a, float b){ h2v h; h[0] = (_Float16)a; h[1] = (_Float16)b; return __builtin_bit_cast(u32, h); }
DEVI u16 f2h(float a){ _Float16 h = (_Float16)a; return __builtin_bit_cast(u16, h); }
DEVI float h2f(u16 a){ return (float)__builtin_bit_cast(_Float16, a); }

#if defined(__has_builtin)
#if __has_builtin(__builtin_amdgcn_fdot2)
#define HAVE_FDOT2 1
#endif
#endif

DEVI float dot2(u32 w, u32 x, float c){
#ifdef HAVE_FDOT2
  return __builtin_amdgcn_fdot2(__builtin_bit_cast(h2v, w), __builtin_bit_cast(h2v, x), c, false);
#else
  h2v a = __builtin_bit_cast(h2v, w), b = __builtin_bit_cast(h2v, x);
  c = fmaf((float)a[0], (float)b[0], c);
  return fmaf((float)a[1], (float)b[1], c);
#endif
}

DEVI float fsig(float x){ return 1.f / (1.f + __expf(-x)); }
DEVI float ftanh(float x){
  x = fminf(12.f, fmaxf(-12.f, x));
  float e = __expf(2.f * x);
  return (e - 1.f) / (e + 1.f);
}

// ---------------- weight repack kernels ----------------

// gru_Wih (3,2,1536,1024) f32 -> WgT[(l*512+kd)*3072 + (d*1536+g)]  f16 pair (k=2kd,2kd+1)
__global__ void k_pack_wih(const float* __restrict__ W, u32* __restrict__ out){
  int idx = blockIdx.x * 256 + threadIdx.x;   // 3*2*1536*512 = 4,718,592
  int kd = idx & 511;
  int q = idx >> 9;          // q = (l*2+d)*1536 + g
  int g = q % 1536;
  int ld = q / 1536;
  const float* src = W + (size_t)q * 1024 + kd * 2;
  int l = ld >> 1, d = ld & 1;
  int n = d * 1536 + g;
  out[(size_t)(l * 512 + kd) * 3072 + n] = pack2f(src[0], src[1]);
}

// gru_Whh (3,2,1536,512) f32 -> Wr[((ld*16+w)*96 + rr)*256 + p]
// rr = gate*32 + u%32, w = u/32; p = ((kd4 ^ (rr&7))<<2) | j  (tile swizzle for b128)
__global__ void k_pack_whh(const float* __restrict__ W, u32* __restrict__ out){
  int idx = blockIdx.x * 256 + threadIdx.x;   // 3*2*1536*256 = 2,359,296
  int kp = idx & 255;
  int q = idx >> 8;          // (l*2+d)*1536 + g
  int g = q % 1536;
  int ld = q / 1536;
  const float* src = W + (size_t)q * 512 + kp * 2;
  int gate = g >> 9, u = g & 511;
  int w = u >> 5, uu = u & 31;
  int rr = gate * 32 + uu;
  int kd4 = kp >> 2, j = kp & 3;
  int p = (((kd4 ^ (rr & 7)) & 63) << 2) | j;
  out[(size_t)((ld * 16 + w) * 96 + rr) * 256 + p] = pack2f(src[0], src[1]);
}

// Wih1 (4,2,128,256) -> wp1[(j*128+kd)*256 + (d*128+i)] ; fc_W (61,1024) -> fcT[kd*64+o]
__global__ void k_pack_misc(const float* __restrict__ Wih1, const float* __restrict__ fcW,
                            u32* __restrict__ wp1, u32* __restrict__ fcT){
  int idx = blockIdx.x * 256 + threadIdx.x;
  if (idx < 131072){
    int c = idx & 255; int q = idx >> 8; int kd = q & 127; int j = q >> 7;
    int d = c >> 7, i = c & 127;
    const float* src = Wih1 + ((size_t)(j * 2 + d) * 128 + i) * 256 + kd * 2;
    wp1[idx] = pack2f(src[0], src[1]);
  } else if (idx < 131072 + 32768){
    int e = idx - 131072;
    int o = e & 63, kd = e >> 6;
    u32 v = 0;
    if (o < 61) v = pack2f(fcW[o * 1024 + kd * 2], fcW[o * 1024 + kd * 2 + 1]);
    fcT[e] = v;
  }
}

// ---------------- stage 1: per-frame biRNNs ----------------

// Layer-1 biRNN, gx fused (K=16). grid 256 = (j,d)<<5 | fblock ; block 256 (2 groups x 128 units)
__global__ __launch_bounds__(256) void k_rnn1(const float* __restrict__ batch,
    const float* __restrict__ Wih0, const float* __restrict__ Whh0,
    const float* __restrict__ bih0, const float* __restrict__ bhh0,
    u16* __restrict__ y1h){
  int bid = blockIdx.x;
  int jd = bid >> 5, fb = bid & 31;
  int j = jd >> 1, d = jd & 1;
  __shared__ float Wi[16][129];
  __shared__ float Wh[128][129];
  __shared__ float hA[8][128];
  __shared__ float hB[8][128];
  __shared__ float xf[8][3][16];
  int tid = threadIdx.x;
  for (int e = tid; e < 2048; e += 256){ int i = e >> 4, k = e & 15; Wi[k][i] = Wih0[(jd * 128 + i) * 16 + k]; }
  for (int e = tid; e < 16384; e += 256){ int i = e >> 7, k = e & 127; Wh[k][i] = Whh0[(jd * 128 + i) * 128 + k]; }
  int i = tid & 127, p = tid >> 7;
  float bias = bih0[jd * 128 + i] + bhh0[jd * 128 + i];
  __syncthreads();
  for (int g8 = 0; g8 < 8; ++g8){
    int f0 = fb * 64 + g8 * 8;
    for (int e = tid; e < 384; e += 256){
      int q = e / 48, r = e % 48, t = r >> 4, k = r & 15;
      int f = f0 + q, b = f >> 8, fr = f & 255;
      xf[q][t][k] = batch[((size_t)b * 768 + fr * 3 + t) * 64 + j * 16 + k];
    }
    __syncthreads();
    int q0 = p * 4;
    for (int tt = 0; tt < 3; ++tt){
      int ta = d ? 2 - tt : tt;
      float a0 = bias, a1 = bias, a2 = bias, a3 = bias;
      #pragma unroll
      for (int k = 0; k < 16; ++k){
        float w = Wi[k][i];
        a0 = fmaf(w, xf[q0 + 0][ta][k], a0);
        a1 = fmaf(w, xf[q0 + 1][ta][k], a1);
        a2 = fmaf(w, xf[q0 + 2][ta][k], a2);
        a3 = fmaf(w, xf[q0 + 3][ta][k], a3);
      }
      if (tt > 0){
        float (*hr)[128] = (tt == 1) ? hA : hB;
        #pragma unroll 4
        for (int k = 0; k < 128; ++k){
          float w = Wh[k][i];
          a0 = fmaf(w, hr[q0 + 0][k], a0);
          a1 = fmaf(w, hr[q0 + 1][k], a1);
          a2 = fmaf(w, hr[q0 + 2][k], a2);
          a3 = fmaf(w, hr[q0 + 3][k], a3);
        }
      }
      float h0 = ftanh(a0), h1 = ftanh(a1), hh2 = ftanh(a2), h3 = ftanh(a3);
      float (*hw)[128] = (tt & 1) ? hB : hA;
      hw[q0 + 0][i] = h0; hw[q0 + 1][i] = h1; hw[q0 + 2][i] = hh2; hw[q0 + 3][i] = h3;
      size_t obase = ((size_t)(j * 2048 + f0) * 3 + ta) * 256 + d * 128 + i;
      y1h[obase + (size_t)(q0 + 0) * 768] = f2h(h0);
      y1h[obase + (size_t)(q0 + 1) * 768] = f2h(h1);
      y1h[obase + (size_t)(q0 + 2) * 768] = f2h(hh2);
      y1h[obase + (size_t)(q0 + 3) * 768] = f2h(h3);
      __syncthreads();
    }
  }
}

// gx2 = y1 @ Wih1^T + bih1 + bhh1. grid (384 rowtiles, 4 j); block 256 (c = d*128+i)
__global__ __launch_bounds__(256) void k_gx2(const u16* __restrict__ y1h,
    const u32* __restrict__ Wp1, const float* __restrict__ bih1,
    const float* __restrict__ bhh1, u16* __restrict__ gx2h){
  int j = blockIdx.y;
  int rt0 = blockIdx.x * 16;
  __shared__ u32 yL[16][128];
  int tid = threadIdx.x;
  const u32* y1d = (const u32*)y1h;
  for (int e = tid; e < 2048; e += 256){
    int rr = e >> 7, kd = e & 127;
    yL[rr][kd] = y1d[(size_t)(j * 6144 + rt0 + rr) * 128 + kd];
  }
  __syncthreads();
  int c = tid, d = c >> 7, i = c & 127;
  float acc[16];
  #pragma unroll
  for (int rr = 0; rr < 16; ++rr) acc[rr] = 0.f;
  const u32* wp = Wp1 + (size_t)j * 128 * 256 + c;
  for (int kd = 0; kd < 128; ++kd){
    u32 w = wp[(size_t)kd * 256];
    #pragma unroll
    for (int rr = 0; rr < 16; ++rr) acc[rr] = dot2(w, yL[rr][kd], acc[rr]);
  }
  float bias = bih1[(j * 2 + d) * 128 + i] + bhh1[(j * 2 + d) * 128 + i];
  #pragma unroll
  for (int rr = 0; rr < 16; ++rr)
    gx2h[(size_t)(j * 6144 + rt0 + rr) * 256 + c] = f2h(acc[rr] + bias);
}

// Layer-2: fwd 3-step recurrence; bwd = tanh(gx2[t=2]) single step. grid 128 = j<<5|fb, block 256
__global__ __launch_bounds__(256) void k_rnn2(const u16* __restrict__ gx2h,
    const float* __restrict__ Whh1, u16* __restrict__ x0h){
  int bid = blockIdx.x;
  int j = bid >> 5, fb = bid & 31;
  __shared__ float Wh[128][129];
  __shared__ float hA[8][128];
  __shared__ float hB[8][128];
  int tid = threadIdx.x;
  for (int e = tid; e < 16384; e += 256){ int i = e >> 7, k = e & 127; Wh[k][i] = Whh1[((size_t)(j * 2) * 128 + i) * 128 + k]; }
  int i = tid & 127, p = tid >> 7, q0 = p * 4;
  __syncthreads();
  for (int g8 = 0; g8 < 8; ++g8){
    int f0 = fb * 64 + g8 * 8;
    for (int tt = 0; tt < 3; ++tt){
      float a0 = h2f(gx2h[(size_t)(j * 6144 + (f0 + q0 + 0) * 3 + tt) * 256 + i]);
      float a1 = h2f(gx2h[(size_t)(j * 6144 + (f0 + q0 + 1) * 3 + tt) * 256 + i]);
      float a2 = h2f(gx2h[(size_t)(j * 6144 + (f0 + q0 + 2) * 3 + tt) * 256 + i]);
      float a3 = h2f(gx2h[(size_t)(j * 6144 + (f0 + q0 + 3) * 3 + tt) * 256 + i]);
      if (tt > 0){
        float (*hr)[128] = (tt == 1) ? hA : hB;
        #pragma unroll 4
        for (int k = 0; k < 128; ++k){
          float w = Wh[k][i];
          a0 = fmaf(w, hr[q0 + 0][k], a0);
          a1 = fmaf(w, hr[q0 + 1][k], a1);
          a2 = fmaf(w, hr[q0 + 2][k], a2);
          a3 = fmaf(w, hr[q0 + 3][k], a3);
        }
      }
      float h0 = ftanh(a0), h1 = ftanh(a1), hh2 = ftanh(a2), h3 = ftanh(a3);
      float (*hw)[128] = (tt & 1) ? hB : hA;
      hw[q0 + 0][i] = h0; hw[q0 + 1][i] = h1; hw[q0 + 2][i] = hh2; hw[q0 + 3][i] = h3;
      if (tt == 2){
        #pragma unroll
        for (int qq = 0; qq < 4; ++qq){
          int f = f0 + q0 + qq;
          float hv = (qq == 0) ? h0 : (qq == 1) ? h1 : (qq == 2) ? hh2 : h3;
          x0h[(size_t)f * 1024 + j * 256 + i] = f2h(hv);
          float bv = ftanh(h2f(gx2h[(size_t)(j * 6144 + f * 3 + 2) * 256 + 128 + i]));
          x0h[(size_t)f * 1024 + j * 256 + 128 + i] = f2h(bv);
        }
      }
      __syncthreads();
    }
  }
}

// ---------------- GRU stack ----------------

// gx = x @ Wih^T + bih (+bhh for r,z). grid (12 ntiles, 128 = b<<4|ttile); block 256
__global__ __launch_bounds__(256) void k_gru_gx(int l, const u16* __restrict__ xin,
    const u32* __restrict__ WgT, const float* __restrict__ gbih,
    const float* __restrict__ gbhh, const int* __restrict__ lengths,
    u16* __restrict__ gxh){
  int b = blockIdx.y >> 4, t0 = (blockIdx.y & 15) * 16;
  int nf = lengths[b] / 3;
  if (t0 >= nf) return;
  __shared__ u32 xL[16][512];
  int tid = threadIdx.x;
  const u32* xd = (const u32*)xin;
  for (int e = tid; e < 8192; e += 256){
    int rr = e >> 9, kd = e & 511;
    xL[rr][kd] = xd[(size_t)(b * 256 + t0 + rr) * 512 + kd];
  }
  __syncthreads();
  int n = blockIdx.x * 256 + tid;
  int d = (n >= 1536) ? 1 : 0;
  int g = n - d * 1536;
  float acc[16];
  #pragma unroll
  for (int rr = 0; rr < 16; ++rr) acc[rr] = 0.f;
  const u32* wp = WgT + (size_t)l * 512 * 3072 + n;
  for (int kd = 0; kd < 512; ++kd){
    u32 w = wp[(size_t)kd * 3072];
    #pragma unroll
    for (int rr = 0; rr < 16; ++rr) acc[rr] = dot2(w, xL[rr][kd], acc[rr]);
  }
  int ld = l * 2 + d;
  float bias = gbih[ld * 1536 + g] + ((g < 1024) ? gbhh[ld * 1536 + g] : 0.f);
  #pragma unroll
  for (int rr = 0; rr < 16; ++rr)
    gxh[(size_t)((d * 8 + b) * 256 + t0 + rr) * 1536 + g] = f2h(acc[rr] + bias);
}

// GRU recurrence v3: tagged-word sync (1 IC trip), full-K rows, b128 LDS reads.
// grid 256 = d<<7 | b<<4 | w ; block 128 (thread = row rr, rows 0..95 active)
__global__ __launch_bounds__(128, 1) void k_gru_rec(int l, const u16* __restrict__ gxh,
    const float* __restrict__ gbhh, const int* __restrict__ lengths,
    const u32* __restrict__ Wr, u64* __restrict__ hpk, u16* __restrict__ xout){
  int bid = blockIdx.x;
  int w = bid & 15, b = (bid >> 4) & 7, d = bid >> 7;
  int chain = d * 8 + b;
  int nf = lengths[b] / 3;
  int tid = threadIdx.x;          // 0..127
  int u0 = w * 32;
  __shared__ __align__(16) u32 WL[24576];   // 96 KB: [rr][256], tile-swizzled
  __shared__ __align__(16) u32 hL[256];
  __shared__ float dotv[96];
  // stage this WG's 96x512 f16 weight slice into LDS once (contiguous b128 copy)
  const float4* wsrc = (const float4*)(Wr + (size_t)((l * 2 + d) * 16 + w) * 24576);
  float4* wdst = (float4*)WL;
  for (int e = tid; e < 6144; e += 128) wdst[e] = wsrc[e];
  u64* hpl = hpk + (size_t)l * 8192;        // [slot2][chain16][256] u64 per layer
  const u16* gxb = gxh + (size_t)chain * 256 * 1536;
  float bhn = (tid < 32) ? gbhh[(l * 2 + d) * 1536 + 1024 + u0 + tid] : 0.f;
  int rr = (tid < 96) ? tid : 95;
  const u32* wrow = WL + rr * 256;
  int swz = rr & 7;
  float hprev = 0.f;               // lane-owned unit state, exact f32 across steps
  __syncthreads();
  for (int st = 0; st < nf; ++st){
    int t = d ? (nf - 1 - st) : st;
    // prefetch this step's gx (independent of the sync) to hide load latency
    float gr = 0.f, gz = 0.f, gn = 0.f;
    if (tid < 32){
      const u16* gxr = gxb + (size_t)t * 1536 + u0 + tid;
      gr = h2f(gxr[0]); gz = h2f(gxr[512]); gn = h2f(gxr[1024]);
    }
    // poll own tagged words until step st's h has landed (tag == st)
    {
      u64* base = hpl + (size_t)(st & 1) * 4096 + chain * 256;
      u64 v0, v1; int gd = 0;
      do { v0 = __hip_atomic_load(&base[tid], __ATOMIC_RELAXED, __HIP_MEMORY_SCOPE_AGENT); }
      while ((int)(v0 >> 32) < st && ++gd < (1 << 24));
      gd = 0;
      do { v1 = __hip_atomic_load(&base[tid + 128], __ATOMIC_RELAXED, __HIP_MEMORY_SCOPE_AGENT); }
      while ((int)(v1 >> 32) < st && ++gd < (1 << 24));
      hL[tid] = (u32)v0; hL[tid + 128] = (u32)v1;
    }
    __syncthreads();
    // full-K dot for row rr: 64 tiles x (1 swizzled b128 W read + 1 uniform b128 h read + 4 dot2)
    float a0 = 0.f, a1 = 0.f, a2 = 0.f, a3 = 0.f;
    const uint4* h4 = (const uint4*)hL;
    #pragma unroll 8
    for (int t4 = 0; t4 < 64; ++t4){
      uint4 hv = h4[t4];
      uint4 wv = *(const uint4*)(wrow + (((t4 & 56) | ((t4 ^ swz) & 7)) << 2));
      a0 = dot2(wv.x, hv.x, a0);
      a1 = dot2(wv.y, hv.y, a1);
      a2 = dot2(wv.z, hv.z, a2);
      a3 = dot2(wv.w, hv.w, a3);
    }
    if (tid < 96) dotv[tid] = (a0 + a1) + (a2 + a3);
    __syncthreads();
    float hnew = 0.f;
    if (tid < 32){
      float rg = fsig(dotv[tid] + gr);
      float zg = fsig(dotv[tid + 32] + gz);
      float ng = ftanh(gn + rg * (dotv[tid + 64] + bhn));
      hnew = (1.f - zg) * ng + zg * hprev;
      hprev = hnew;
      xout[(size_t)(b * 256 + t) * 1024 + d * 512 + u0 + tid] = f2h(hnew);
    }
    // publish h_{st+1}: self-validating {tag, data} words — no fence, no flag
    float ha = __shfl(hnew, (tid & 15) * 2);
    float hb = __shfl(hnew, (tid & 15) * 2 + 1);
    if (tid < 16){
      u64 v = ((u64)(u32)(st + 1) << 32) | (u64)pack2f(ha, hb);
      __hip_atomic_store(&hpl[(size_t)((st + 1) & 1) * 4096 + chain * 256 + (u0 >> 1) + tid],
                         v, __ATOMIC_RELAXED, __HIP_MEMORY_SCOPE_AGENT);
    }
    // no trailing barrier needed: next hL write is gated by the dotv barrier,
    // and next dotv write is gated by the next hL barrier.
  }
}

// FC + packed gather. grid 256 = b<<5 | ttile ; block 256 = (ks = tid>>6) x (o = tid&63)
__global__ __launch_bounds__(256) void k_fc(const u16* __restrict__ x2h,
    const u32* __restrict__ fcT, const float* __restrict__ fcb,
    const int* __restrict__ lengths, float* __restrict__ out){
  int bid = blockIdx.x;
  int b = bid >> 5, t0 = (bid & 31) * 8;
  int nf = lengths[b] / 3;
  if (t0 >= nf) return;
  int off = 0;
  for (int b2 = 0; b2 < b; ++b2) off += lengths[b2] / 3;
  __shared__ u32 xL[512];
  __shared__ float redf[4][64];
  int tid = threadIdx.x;
  int o = tid & 63, ks = tid >> 6;
  const u32* xd = (const u32*)x2h;
  int tend = (t0 + 8 < nf) ? (t0 + 8) : nf;
  for (int t = t0; t < tend; ++t){
    for (int e = tid; e < 512; e += 256) xL[e] = xd[(size_t)(b * 256 + t) * 512 + e];
    __syncthreads();
    float acc = 0.f;
    const u32* fp = fcT + ks * 128 * 64 + o;
    #pragma unroll 4
    for (int kd = 0; kd < 128; ++kd)
      acc = dot2(fp[kd * 64], xL[ks * 128 + kd], acc);
    redf[ks][o] = acc;
    __syncthreads();
    if (ks == 0 && o < 61)
      out[(size_t)(off + t) * 61 + o] = redf[0][o] + redf[1][o] + redf[2][o] + redf[3][o] + fcb[o];
    __syncthreads();
  }
}

// ---------------- host ----------------

static constexpr size_t alignup(size_t x){ return (x + 255) & ~(size_t)255; }

extern "C" void kernel_launch(void* const* d_in, const int* in_sizes, int n_in,
                              void* d_out, int out_size, void* d_ws, size_t ws_size,
                              hipStream_t stream){
  const float* batch = (const float*)d_in[0];
  const int* lengths = (const int*)d_in[1];
  const float* Wih0 = (const float*)d_in[2];
  const float* Whh0 = (const float*)d_in[3];
  const float* bih0 = (const float*)d_in[4];
  const float* bhh0 = (const float*)d_in[5];
  const float* Wih1 = (const float*)d_in[6];
  const float* Whh1 = (const float*)d_in[7];
  const float* bih1 = (const float*)d_in[8];
  const float* bhh1 = (const float*)d_in[9];
  const float* gWih = (const float*)d_in[10];
  const float* gWhh = (const float*)d_in[11];
  const float* gbih = (const float*)d_in[12];
  const float* gbhh = (const float*)d_in[13];
  const float* fcW  = (const float*)d_in[14];
  const float* fcb  = (const float*)d_in[15];

  char* ws = (char*)d_ws;
  size_t off = 0;
  const size_t O_HPK  = off; off = alignup(off + (size_t)3 * 2 * 16 * 256 * 8);
  const size_t SYNC_BYTES = off;                       // zero [0, off) every launch
  const size_t O_Y1H  = off; off = alignup(off + (size_t)4 * 2048 * 3 * 256 * 2);
  const size_t O_GX2H = off; off = alignup(off + (size_t)4 * 2048 * 3 * 256 * 2);
  const size_t O_X0   = off; off = alignup(off + (size_t)8 * 256 * 1024 * 2);
  const size_t O_X1   = off; off = alignup(off + (size_t)8 * 256 * 1024 * 2);
  const size_t O_X2   = off; off = alignup(off + (size_t)8 * 256 * 1024 * 2);
  const size_t O_GXH  = off; off = alignup(off + (size_t)2 * 8 * 256 * 1536 * 2);
  const size_t O_WGT  = off; off = alignup(off + (size_t)3 * 512 * 3072 * 4);
  const size_t O_WRH  = off; off = alignup(off + (size_t)3 * 2 * 16 * 96 * 256 * 4);
  const size_t O_WP1  = off; off = alignup(off + (size_t)4 * 128 * 256 * 4);
  const size_t O_FCT  = off; off = alignup(off + (size_t)512 * 64 * 4);
  (void)ws_size; (void)in_sizes; (void)n_in; (void)out_size;

  u64* HPK  = (u64*)(ws + O_HPK);
  u16* Y1H  = (u16*)(ws + O_Y1H);
  u16* GX2H = (u16*)(ws + O_GX2H);
  u16* X0   = (u16*)(ws + O_X0);
  u16* X1   = (u16*)(ws + O_X1);
  u16* X2   = (u16*)(ws + O_X2);
  u16* GXH  = (u16*)(ws + O_GXH);
  u32* WGT  = (u32*)(ws + O_WGT);
  u32* WRH  = (u32*)(ws + O_WRH);
  u32* WP1  = (u32*)(ws + O_WP1);
  u32* FCT  = (u32*)(ws + O_FCT);

  hipMemsetAsync(ws, 0, SYNC_BYTES, stream);

  k_pack_wih <<<18432, 256, 0, stream>>>(gWih, WGT);
  k_pack_whh <<<9216, 256, 0, stream>>>(gWhh, WRH);
  k_pack_misc<<<640, 256, 0, stream>>>(Wih1, fcW, WP1, FCT);

  k_rnn1<<<256, 256, 0, stream>>>(batch, Wih0, Whh0, bih0, bhh0, Y1H);
  k_gx2 <<<dim3(384, 4), 256, 0, stream>>>(Y1H, WP1, bih1, bhh1, GX2H);
  k_rnn2<<<128, 256, 0, stream>>>(GX2H, Whh1, X0);

  u16* X[3] = { X0, X1, X2 };
  for (int l = 0; l < 3; ++l){
    u16* xin = X[l];
    u16* xout = X[(l + 1) % 3];
    k_gru_gx <<<dim3(12, 128), 256, 0, stream>>>(l, xin, WGT, gbih, gbhh, lengths, GXH);
    k_gru_rec<<<256, 128, 0, stream>>>(l, GXH, gbhh, lengths, WRH, HPK, xout);
  }
  k_fc<<<256, 256, 0, stream>>>(X[0], FCT, fcb, lengths, (float*)d_out);
}

// Round 6
// 2449.047 us; speedup vs baseline: 7.9407x; 1.1882x over previous
//
#include <hip/hip_runtime.h>

typedef unsigned int u32;
typedef unsigned short u16;
typedef unsigned long long u64;
typedef _Float16 h2v __attribute__((ext_vector_type(2)));

#define DEVI static __device__ __forceinline__

DEVI u32 pack2f(float a, float b){ h2v h; h[0] = (_Float16)a; h[1] = (_Float16)b; return __builtin_bit_cast(u32, h); }
DEVI u16 f2h(float a){ _Float16 h = (_Float16)a; return __builtin_bit_cast(u16, h); }
DEVI float h2f(u16 a){ return (float)__builtin_bit_cast(_Float16, a); }

#if defined(__has_builtin)
#if __has_builtin(__builtin_amdgcn_fdot2)
#define HAVE_FDOT2 1
#endif
#endif

DEVI float dot2(u32 w, u32 x, float c){
#ifdef HAVE_FDOT2
  return __builtin_amdgcn_fdot2(__builtin_bit_cast(h2v, w), __builtin_bit_cast(h2v, x), c, false);
#else
  h2v a = __builtin_bit_cast(h2v, w), b = __builtin_bit_cast(h2v, x);
  c = fmaf((float)a[0], (float)b[0], c);
  return fmaf((float)a[1], (float)b[1], c);
#endif
}

DEVI float fsig(float x){ return 1.f / (1.f + __expf(-x)); }
DEVI float ftanh(float x){
  x = fminf(12.f, fmaxf(-12.f, x));
  float e = __expf(2.f * x);
  return (e - 1.f) / (e + 1.f);
}

// ---------------- weight repack kernels ----------------

// gru_Wih (3,2,1536,1024) f32 -> WgT[(l*512+kd)*3072 + (d*1536+g)]  f16 pair (k=2kd,2kd+1)
__global__ void k_pack_wih(const float* __restrict__ W, u32* __restrict__ out){
  int idx = blockIdx.x * 256 + threadIdx.x;   // 3*2*1536*512 = 4,718,592
  int kd = idx & 511;
  int q = idx >> 9;          // q = (l*2+d)*1536 + g
  int g = q % 1536;
  int ld = q / 1536;
  const float* src = W + (size_t)q * 1024 + kd * 2;
  int l = ld >> 1, d = ld & 1;
  int n = d * 1536 + g;
  out[(size_t)(l * 512 + kd) * 3072 + n] = pack2f(src[0], src[1]);
}

// gru_Whh (3,2,1536,512) f32 -> Wr[((ld*16+w)*96 + rr)*256 + p]
// rr = gate*32 + u%32, w = u/32; p = ((kd4 ^ (rr&7))<<2) | j  (tile swizzle for b128)
__global__ void k_pack_whh(const float* __restrict__ W, u32* __restrict__ out){
  int idx = blockIdx.x * 256 + threadIdx.x;   // 3*2*1536*256 = 2,359,296
  int kp = idx & 255;
  int q = idx >> 8;          // (l*2+d)*1536 + g
  int g = q % 1536;
  int ld = q / 1536;
  const float* src = W + (size_t)q * 512 + kp * 2;
  int gate = g >> 9, u = g & 511;
  int w = u >> 5, uu = u & 31;
  int rr = gate * 32 + uu;
  int kd4 = kp >> 2, j = kp & 3;
  int p = (((kd4 ^ (rr & 7)) & 63) << 2) | j;
  out[(size_t)((ld * 16 + w) * 96 + rr) * 256 + p] = pack2f(src[0], src[1]);
}

// Wih1 (4,2,128,256) -> wp1[(j*128+kd)*256 + (d*128+i)] ; fc_W (61,1024) -> fcT[kd*64+o]
__global__ void k_pack_misc(const float* __restrict__ Wih1, const float* __restrict__ fcW,
                            u32* __restrict__ wp1, u32* __restrict__ fcT){
  int idx = blockIdx.x * 256 + threadIdx.x;
  if (idx < 131072){
    int c = idx & 255; int q = idx >> 8; int kd = q & 127; int j = q >> 7;
    int d = c >> 7, i = c & 127;
    const float* src = Wih1 + ((size_t)(j * 2 + d) * 128 + i) * 256 + kd * 2;
    wp1[idx] = pack2f(src[0], src[1]);
  } else if (idx < 131072 + 32768){
    int e = idx - 131072;
    int o = e & 63, kd = e >> 6;
    u32 v = 0;
    if (o < 61) v = pack2f(fcW[o * 1024 + kd * 2], fcW[o * 1024 + kd * 2 + 1]);
    fcT[e] = v;
  }
}

// ---------------- stage 1: per-frame biRNNs ----------------

// Layer-1 biRNN, gx fused (K=16). grid 256 = (j,d)<<5 | fblock ; block 256 (2 groups x 128 units)
__global__ __launch_bounds__(256) void k_rnn1(const float* __restrict__ batch,
    const float* __restrict__ Wih0, const float* __restrict__ Whh0,
    const float* __restrict__ bih0, const float* __restrict__ bhh0,
    u16* __restrict__ y1h){
  int bid = blockIdx.x;
  int jd = bid >> 5, fb = bid & 31;
  int j = jd >> 1, d = jd & 1;
  __shared__ float Wi[16][129];
  __shared__ float Wh[128][129];
  __shared__ float hA[8][128];
  __shared__ float hB[8][128];
  __shared__ float xf[8][3][16];
  int tid = threadIdx.x;
  for (int e = tid; e < 2048; e += 256){ int i = e >> 4, k = e & 15; Wi[k][i] = Wih0[(jd * 128 + i) * 16 + k]; }
  for (int e = tid; e < 16384; e += 256){ int i = e >> 7, k = e & 127; Wh[k][i] = Whh0[(jd * 128 + i) * 128 + k]; }
  int i = tid & 127, p = tid >> 7;
  float bias = bih0[jd * 128 + i] + bhh0[jd * 128 + i];
  __syncthreads();
  for (int g8 = 0; g8 < 8; ++g8){
    int f0 = fb * 64 + g8 * 8;
    for (int e = tid; e < 384; e += 256){
      int q = e / 48, r = e % 48, t = r >> 4, k = r & 15;
      int f = f0 + q, b = f >> 8, fr = f & 255;
      xf[q][t][k] = batch[((size_t)b * 768 + fr * 3 + t) * 64 + j * 16 + k];
    }
    __syncthreads();
    int q0 = p * 4;
    for (int tt = 0; tt < 3; ++tt){
      int ta = d ? 2 - tt : tt;
      float a0 = bias, a1 = bias, a2 = bias, a3 = bias;
      #pragma unroll
      for (int k = 0; k < 16; ++k){
        float w = Wi[k][i];
        a0 = fmaf(w, xf[q0 + 0][ta][k], a0);
        a1 = fmaf(w, xf[q0 + 1][ta][k], a1);
        a2 = fmaf(w, xf[q0 + 2][ta][k], a2);
        a3 = fmaf(w, xf[q0 + 3][ta][k], a3);
      }
      if (tt > 0){
        float (*hr)[128] = (tt == 1) ? hA : hB;
        #pragma unroll 4
        for (int k = 0; k < 128; ++k){
          float w = Wh[k][i];
          a0 = fmaf(w, hr[q0 + 0][k], a0);
          a1 = fmaf(w, hr[q0 + 1][k], a1);
          a2 = fmaf(w, hr[q0 + 2][k], a2);
          a3 = fmaf(w, hr[q0 + 3][k], a3);
        }
      }
      float h0 = ftanh(a0), h1 = ftanh(a1), hh2 = ftanh(a2), h3 = ftanh(a3);
      float (*hw)[128] = (tt & 1) ? hB : hA;
      hw[q0 + 0][i] = h0; hw[q0 + 1][i] = h1; hw[q0 + 2][i] = hh2; hw[q0 + 3][i] = h3;
      size_t obase = ((size_t)(j * 2048 + f0) * 3 + ta) * 256 + d * 128 + i;
      y1h[obase + (size_t)(q0 + 0) * 768] = f2h(h0);
      y1h[obase + (size_t)(q0 + 1) * 768] = f2h(h1);
      y1h[obase + (size_t)(q0 + 2) * 768] = f2h(hh2);
      y1h[obase + (size_t)(q0 + 3) * 768] = f2h(h3);
      __syncthreads();
    }
  }
}

// gx2 = y1 @ Wih1^T + bih1 + bhh1. grid (384 rowtiles, 4 j); block 256 (c = d*128+i)
__global__ __launch_bounds__(256) void k_gx2(const u16* __restrict__ y1h,
    const u32* __restrict__ Wp1, const float* __restrict__ bih1,
    const float* __restrict__ bhh1, u16* __restrict__ gx2h){
  int j = blockIdx.y;
  int rt0 = blockIdx.x * 16;
  __shared__ u32 yL[16][128];
  int tid = threadIdx.x;
  const u32* y1d = (const u32*)y1h;
  for (int e = tid; e < 2048; e += 256){
    int rr = e >> 7, kd = e & 127;
    yL[rr][kd] = y1d[(size_t)(j * 6144 + rt0 + rr) * 128 + kd];
  }
  __syncthreads();
  int c = tid, d = c >> 7, i = c & 127;
  float acc[16];
  #pragma unroll
  for (int rr = 0; rr < 16; ++rr) acc[rr] = 0.f;
  const u32* wp = Wp1 + (size_t)j * 128 * 256 + c;
  for (int kd = 0; kd < 128; ++kd){
    u32 w = wp[(size_t)kd * 256];
    #pragma unroll
    for (int rr = 0; rr < 16; ++rr) acc[rr] = dot2(w, yL[rr][kd], acc[rr]);
  }
  float bias = bih1[(j * 2 + d) * 128 + i] + bhh1[(j * 2 + d) * 128 + i];
  #pragma unroll
  for (int rr = 0; rr < 16; ++rr)
    gx2h[(size_t)(j * 6144 + rt0 + rr) * 256 + c] = f2h(acc[rr] + bias);
}

// Layer-2: fwd 3-step recurrence; bwd = tanh(gx2[t=2]) single step. grid 128 = j<<5|fb, block 256
__global__ __launch_bounds__(256) void k_rnn2(const u16* __restrict__ gx2h,
    const float* __restrict__ Whh1, u16* __restrict__ x0h){
  int bid = blockIdx.x;
  int j = bid >> 5, fb = bid & 31;
  __shared__ float Wh[128][129];
  __shared__ float hA[8][128];
  __shared__ float hB[8][128];
  int tid = threadIdx.x;
  for (int e = tid; e < 16384; e += 256){ int i = e >> 7, k = e & 127; Wh[k][i] = Whh1[((size_t)(j * 2) * 128 + i) * 128 + k]; }
  int i = tid & 127, p = tid >> 7, q0 = p * 4;
  __syncthreads();
  for (int g8 = 0; g8 < 8; ++g8){
    int f0 = fb * 64 + g8 * 8;
    for (int tt = 0; tt < 3; ++tt){
      float a0 = h2f(gx2h[(size_t)(j * 6144 + (f0 + q0 + 0) * 3 + tt) * 256 + i]);
      float a1 = h2f(gx2h[(size_t)(j * 6144 + (f0 + q0 + 1) * 3 + tt) * 256 + i]);
      float a2 = h2f(gx2h[(size_t)(j * 6144 + (f0 + q0 + 2) * 3 + tt) * 256 + i]);
      float a3 = h2f(gx2h[(size_t)(j * 6144 + (f0 + q0 + 3) * 3 + tt) * 256 + i]);
      if (tt > 0){
        float (*hr)[128] = (tt == 1) ? hA : hB;
        #pragma unroll 4
        for (int k = 0; k < 128; ++k){
          float w = Wh[k][i];
          a0 = fmaf(w, hr[q0 + 0][k], a0);
          a1 = fmaf(w, hr[q0 + 1][k], a1);
          a2 = fmaf(w, hr[q0 + 2][k], a2);
          a3 = fmaf(w, hr[q0 + 3][k], a3);
        }
      }
      float h0 = ftanh(a0), h1 = ftanh(a1), hh2 = ftanh(a2), h3 = ftanh(a3);
      float (*hw)[128] = (tt & 1) ? hB : hA;
      hw[q0 + 0][i] = h0; hw[q0 + 1][i] = h1; hw[q0 + 2][i] = hh2; hw[q0 + 3][i] = h3;
      if (tt == 2){
        #pragma unroll
        for (int qq = 0; qq < 4; ++qq){
          int f = f0 + q0 + qq;
          float hv = (qq == 0) ? h0 : (qq == 1) ? h1 : (qq == 2) ? hh2 : h3;
          x0h[(size_t)f * 1024 + j * 256 + i] = f2h(hv);
          float bv = ftanh(h2f(gx2h[(size_t)(j * 6144 + f * 3 + 2) * 256 + 128 + i]));
          x0h[(size_t)f * 1024 + j * 256 + 128 + i] = f2h(bv);
        }
      }
      __syncthreads();
    }
  }
}

// ---------------- GRU stack ----------------

// gx = x @ Wih^T + bih (+bhh for r,z). grid (12 ntiles, 128 = b<<4|ttile); block 256
__global__ __launch_bounds__(256) void k_gru_gx(int l, const u16* __restrict__ xin,
    const u32* __restrict__ WgT, const float* __restrict__ gbih,
    const float* __restrict__ gbhh, const int* __restrict__ lengths,
    u16* __restrict__ gxh){
  int b = blockIdx.y >> 4, t0 = (blockIdx.y & 15) * 16;
  int nf = lengths[b] / 3;
  if (t0 >= nf) return;
  __shared__ u32 xL[16][512];
  int tid = threadIdx.x;
  const u32* xd = (const u32*)xin;
  for (int e = tid; e < 8192; e += 256){
    int rr = e >> 9, kd = e & 511;
    xL[rr][kd] = xd[(size_t)(b * 256 + t0 + rr) * 512 + kd];
  }
  __syncthreads();
  int n = blockIdx.x * 256 + tid;
  int d = (n >= 1536) ? 1 : 0;
  int g = n - d * 1536;
  float acc[16];
  #pragma unroll
  for (int rr = 0; rr < 16; ++rr) acc[rr] = 0.f;
  const u32* wp = WgT + (size_t)l * 512 * 3072 + n;
  for (int kd = 0; kd < 512; ++kd){
    u32 w = wp[(size_t)kd * 3072];
    #pragma unroll
    for (int rr = 0; rr < 16; ++rr) acc[rr] = dot2(w, xL[rr][kd], acc[rr]);
  }
  int ld = l * 2 + d;
  float bias = gbih[ld * 1536 + g] + ((g < 1024) ? gbhh[ld * 1536 + g] : 0.f);
  #pragma unroll
  for (int rr = 0; rr < 16; ++rr)
    gxh[(size_t)((d * 8 + b) * 256 + t0 + rr) * 1536 + g] = f2h(acc[rr] + bias);
}

// GRU recurrence v6: round-3 proven agent-scope tagged-u64 sync, plus
// (a) fully parallel poll (256 threads x 1 word) and (b) split-K dot (2 x 96 rows).
// grid 256 = d<<7 | b<<4 | w ; block 256: s = tid>>7 (K-half), r = tid&127 (row).
// hpk u64 words per layer: [slot2][chain16][256] = {tag32 = st | 2xf16}.
__global__ __launch_bounds__(256, 1) void k_gru_rec(int l, const u16* __restrict__ gxh,
    const float* __restrict__ gbhh, const int* __restrict__ lengths,
    const u32* __restrict__ Wr, u64* __restrict__ hpk, u16* __restrict__ xout){
  int bid = blockIdx.x;
  int w = bid & 15, b = (bid >> 4) & 7, d = bid >> 7;
  int chain = d * 8 + b;
  int nf = lengths[b] / 3;
  int tid = threadIdx.x;          // 0..255
  int s = tid >> 7, r = tid & 127;
  int u0 = w * 32;
  __shared__ __align__(16) u32 WL[24576];   // 96 KB: [rr][256], tile-swizzled
  __shared__ __align__(16) u32 hL[256];
  __shared__ float red[96];
  __shared__ float dotv[96];
  // stage this WG's 96x512 f16 weight slice into LDS once (contiguous b128 copy)
  const float4* wsrc = (const float4*)(Wr + (size_t)((l * 2 + d) * 16 + w) * 24576);
  float4* wdst = (float4*)WL;
  for (int e = tid; e < 6144; e += 256) wdst[e] = wsrc[e];
  u64* hpl = hpk + (size_t)l * 8192;        // [slot2][chain16][256] u64 per layer
  const u16* gxb = gxh + (size_t)chain * 256 * 1536;
  float bhn = (tid < 32) ? gbhh[(l * 2 + d) * 1536 + 1024 + u0 + tid] : 0.f;
  int rr = (r < 96) ? r : 95;
  const u32* wrow = WL + rr * 256;
  int swz = rr & 7;
  int tb = s * 32;
  float hprev = 0.f;               // lane-owned unit state, exact f32 across steps
  __syncthreads();
  for (int st = 0; st < nf; ++st){
    int t = d ? (nf - 1 - st) : st;
    // prefetch this step's gx (independent of the sync) to hide load latency
    float gr = 0.f, gz = 0.f, gn = 0.f;
    if (tid < 32){
      const u16* gxr = gxb + (size_t)t * 1536 + u0 + tid;
      gr = h2f(gxr[0]); gz = h2f(gxr[512]); gn = h2f(gxr[1024]);
    }
    // poll own tagged word (one per thread, all 256 in parallel) until tag >= st
    {
      u64* pb = hpl + (size_t)(st & 1) * 4096 + chain * 256;
      u64 v; int gd = 0;
      do { v = __hip_atomic_load(&pb[tid], __ATOMIC_RELAXED, __HIP_MEMORY_SCOPE_AGENT); }
      while ((int)(v >> 32) < st && ++gd < (1 << 17));
      hL[tid] = (u32)v;
    }
    __syncthreads();
    // half-K dot for row rr: 32 tiles x (1 swizzled b128 W read + 1 uniform b128 h read + 4 dot2)
    float a0 = 0.f, a1 = 0.f, a2 = 0.f, a3 = 0.f;
    const uint4* h4 = (const uint4*)hL;
    #pragma unroll 8
    for (int tt = 0; tt < 32; ++tt){
      int t4 = tb + tt;
      uint4 hv = h4[t4];
      uint4 wv = *(const uint4*)(wrow + (((t4 & 56) | ((t4 ^ swz) & 7)) << 2));
      a0 = dot2(wv.x, hv.x, a0);
      a1 = dot2(wv.y, hv.y, a1);
      a2 = dot2(wv.z, hv.z, a2);
      a3 = dot2(wv.w, hv.w, a3);
    }
    float asum = (a0 + a1) + (a2 + a3);
    if (s == 1 && r < 96) red[r] = asum;
    __syncthreads();
    if (s == 0 && r < 96) dotv[r] = asum + red[r];
    __syncthreads();
    float hnew = 0.f;
    if (tid < 32){
      float rg = fsig(dotv[tid] + gr);
      float zg = fsig(dotv[tid + 32] + gz);
      float ng = ftanh(gn + rg * (dotv[tid + 64] + bhn));
      hnew = (1.f - zg) * ng + zg * hprev;
      hprev = hnew;
    }
    // publish h_{st+1}: self-validating {tag, data} words — no fence, no flag
    float ha = __shfl(hnew, (tid & 15) * 2);
    float hb = __shfl(hnew, (tid & 15) * 2 + 1);
    if (tid < 16){
      u64 v = ((u64)(u32)(st + 1) << 32) | (u64)pack2f(ha, hb);
      __hip_atomic_store(&hpl[(size_t)((st + 1) & 1) * 4096 + chain * 256 + (u0 >> 1) + tid],
                         v, __ATOMIC_RELAXED, __HIP_MEMORY_SCOPE_AGENT);
    }
    if (tid < 32)
      xout[(size_t)(b * 256 + t) * 1024 + d * 512 + u0 + tid] = f2h(hnew);
    // no trailing barrier needed: next hL write is gated by the dotv barrier,
    // and next dotv write is gated by the next hL barrier.
  }
}

// FC + packed gather. grid 256 = b<<5 | ttile ; block 256 = (ks = tid>>6) x (o = tid&63)
__global__ __launch_bounds__(256) void k_fc(const u16* __restrict__ x2h,
    const u32* __restrict__ fcT, const float* __restrict__ fcb,
    const int* __restrict__ lengths, float* __restrict__ out){
  int bid = blockIdx.x;
  int b = bid >> 5, t0 = (bid & 31) * 8;
  int nf = lengths[b] / 3;
  if (t0 >= nf) return;
  int off = 0;
  for (int b2 = 0; b2 < b; ++b2) off += lengths[b2] / 3;
  __shared__ u32 xL[512];
  __shared__ float redf[4][64];
  int tid = threadIdx.x;
  int o = tid & 63, ks = tid >> 6;
  const u32* xd = (const u32*)x2h;
  int tend = (t0 + 8 < nf) ? (t0 + 8) : nf;
  for (int t = t0; t < tend; ++t){
    for (int e = tid; e < 512; e += 256) xL[e] = xd[(size_t)(b * 256 + t) * 512 + e];
    __syncthreads();
    float acc = 0.f;
    const u32* fp = fcT + ks * 128 * 64 + o;
    #pragma unroll 4
    for (int kd = 0; kd < 128; ++kd)
      acc = dot2(fp[kd * 64], xL[ks * 128 + kd], acc);
    redf[ks][o] = acc;
    __syncthreads();
    if (ks == 0 && o < 61)
      out[(size_t)(off + t) * 61 + o] = redf[0][o] + redf[1][o] + redf[2][o] + redf[3][o] + fcb[o];
    __syncthreads();
  }
}

// ---------------- host ----------------

static constexpr size_t alignup(size_t x){ return (x + 255) & ~(size_t)255; }

extern "C" void kernel_launch(void* const* d_in, const int* in_sizes, int n_in,
                              void* d_out, int out_size, void* d_ws, size_t ws_size,
                              hipStream_t stream){
  const float* batch = (const float*)d_in[0];
  const int* lengths = (const int*)d_in[1];
  const float* Wih0 = (const float*)d_in[2];
  const float* Whh0 = (const float*)d_in[3];
  const float* bih0 = (const float*)d_in[4];
  const float* bhh0 = (const float*)d_in[5];
  const float* Wih1 = (const float*)d_in[6];
  const float* Whh1 = (const float*)d_in[7];
  const float* bih1 = (const float*)d_in[8];
  const float* bhh1 = (const float*)d_in[9];
  const float* gWih = (const float*)d_in[10];
  const float* gWhh = (const float*)d_in[11];
  const float* gbih = (const float*)d_in[12];
  const float* gbhh = (const float*)d_in[13];
  const float* fcW  = (const float*)d_in[14];
  const float* fcb  = (const float*)d_in[15];

  char* ws = (char*)d_ws;
  size_t off = 0;
  const size_t O_HPK  = off; off = alignup(off + (size_t)3 * 2 * 16 * 256 * 8);
  const size_t SYNC_BYTES = off;                       // zero [0, off) every launch
  const size_t O_Y1H  = off; off = alignup(off + (size_t)4 * 2048 * 3 * 256 * 2);
  const size_t O_GX2H = off; off = alignup(off + (size_t)4 * 2048 * 3 * 256 * 2);
  const size_t O_X0   = off; off = alignup(off + (size_t)8 * 256 * 1024 * 2);
  const size_t O_X1   = off; off = alignup(off + (size_t)8 * 256 * 1024 * 2);
  const size_t O_X2   = off; off = alignup(off + (size_t)8 * 256 * 1024 * 2);
  const size_t O_GXH  = off; off = alignup(off + (size_t)2 * 8 * 256 * 1536 * 2);
  const size_t O_WGT  = off; off = alignup(off + (size_t)3 * 512 * 3072 * 4);
  const size_t O_WRH  = off; off = alignup(off + (size_t)3 * 2 * 16 * 96 * 256 * 4);
  const size_t O_WP1  = off; off = alignup(off + (size_t)4 * 128 * 256 * 4);
  const size_t O_FCT  = off; off = alignup(off + (size_t)512 * 64 * 4);
  (void)ws_size; (void)in_sizes; (void)n_in; (void)out_size;

  u64* HPK  = (u64*)(ws + O_HPK);
  u16* Y1H  = (u16*)(ws + O_Y1H);
  u16* GX2H = (u16*)(ws + O_GX2H);
  u16* X0   = (u16*)(ws + O_X0);
  u16* X1   = (u16*)(ws + O_X1);
  u16* X2   = (u16*)(ws + O_X2);
  u16* GXH  = (u16*)(ws + O_GXH);
  u32* WGT  = (u32*)(ws + O_WGT);
  u32* WRH  = (u32*)(ws + O_WRH);
  u32* WP1  = (u32*)(ws + O_WP1);
  u32* FCT  = (u32*)(ws + O_FCT);

  hipMemsetAsync(ws, 0, SYNC_BYTES, stream);

  k_pack_wih <<<18432, 256, 0, stream>>>(gWih, WGT);
  k_pack_whh <<<9216, 256, 0, stream>>>(gWhh, WRH);
  k_pack_misc<<<640, 256, 0, stream>>>(Wih1, fcW, WP1, FCT);

  k_rnn1<<<256, 256, 0, stream>>>(batch, Wih0, Whh0, bih0, bhh0, Y1H);
  k_gx2 <<<dim3(384, 4), 256, 0, stream>>>(Y1H, WP1, bih1, bhh1, GX2H);
  k_rnn2<<<128, 256, 0, stream>>>(GX2H, Whh1, X0);

  u16* X[3] = { X0, X1, X2 };
  for (int l = 0; l < 3; ++l){
    u16* xin = X[l];
    u16* xout = X[(l + 1) % 3];
    k_gru_gx <<<dim3(12, 128), 256, 0, stream>>>(l, xin, WGT, gbih, gbhh, lengths, GXH);
    k_gru_rec<<<256, 256, 0, stream>>>(l, GXH, gbhh, lengths, WRH, HPK, xout);
  }
  k_fc<<<256, 256, 0, stream>>>(X[0], FCT, fcb, lengths, (float*)d_out);
}

// Round 7
// 2184.705 us; speedup vs baseline: 8.9016x; 1.1210x over previous
//
#include <hip/hip_runtime.h>

typedef unsigned int u32;
typedef unsigned short u16;
typedef unsigned long long u64;
typedef _Float16 h2v __attribute__((ext_vector_type(2)));

#define DEVI static __device__ __forceinline__

DEVI u32 pack2f(float a, float b){ h2v h; h[0] = (_Float16)a; h[1] = (_Float16)b; return __builtin_bit_cast(u32, h); }
DEVI u16 f2h(float a){ _Float16 h = (_Float16)a; return __builtin_bit_cast(u16, h); }
DEVI float h2f(u16 a){ return (float)__builtin_bit_cast(_Float16, a); }

#if defined(__has_builtin)
#if __has_builtin(__builtin_amdgcn_fdot2)
#define HAVE_FDOT2 1
#endif
#endif

DEVI float dot2(u32 w, u32 x, float c){
#ifdef HAVE_FDOT2
  return __builtin_amdgcn_fdot2(__builtin_bit_cast(h2v, w), __builtin_bit_cast(h2v, x), c, false);
#else
  h2v a = __builtin_bit_cast(h2v, w), b = __builtin_bit_cast(h2v, x);
  c = fmaf((float)a[0], (float)b[0], c);
  return fmaf((float)a[1], (float)b[1], c);
#endif
}

DEVI float fsig(float x){ return 1.f / (1.f + __expf(-x)); }
DEVI float ftanh(float x){
  x = fminf(12.f, fmaxf(-12.f, x));
  float e = __expf(2.f * x);
  return (e - 1.f) / (e + 1.f);
}

// ---------------- weight repack kernels ----------------

// gru_Wih (3,2,1536,1024) f32 -> WgT[(l*512+kd)*3072 + (d*1536+g)]  f16 pair (k=2kd,2kd+1)
__global__ void k_pack_wih(const float* __restrict__ W, u32* __restrict__ out){
  int idx = blockIdx.x * 256 + threadIdx.x;   // 3*2*1536*512 = 4,718,592
  int kd = idx & 511;
  int q = idx >> 9;          // q = (l*2+d)*1536 + g
  int g = q % 1536;
  int ld = q / 1536;
  const float* src = W + (size_t)q * 1024 + kd * 2;
  int l = ld >> 1, d = ld & 1;
  int n = d * 1536 + g;
  out[(size_t)(l * 512 + kd) * 3072 + n] = pack2f(src[0], src[1]);
}

// gru_Whh (3,2,1536,512) f32 -> Wr[((ld*16+w)*96 + rr)*256 + p]
// rr = gate*32 + u%32, w = u/32; p = ((kd4 ^ (rr&7))<<2) | j  (tile swizzle for b128)
__global__ void k_pack_whh(const float* __restrict__ W, u32* __restrict__ out){
  int idx = blockIdx.x * 256 + threadIdx.x;   // 3*2*1536*256 = 2,359,296
  int kp = idx & 255;
  int q = idx >> 8;          // (l*2+d)*1536 + g
  int g = q % 1536;
  int ld = q / 1536;
  const float* src = W + (size_t)q * 512 + kp * 2;
  int gate = g >> 9, u = g & 511;
  int w = u >> 5, uu = u & 31;
  int rr = gate * 32 + uu;
  int kd4 = kp >> 2, j = kp & 3;
  int p = (((kd4 ^ (rr & 7)) & 63) << 2) | j;
  out[(size_t)((ld * 16 + w) * 96 + rr) * 256 + p] = pack2f(src[0], src[1]);
}

// Wih1 (4,2,128,256) -> wp1[(j*128+kd)*256 + (d*128+i)] ; fc_W (61,1024) -> fcT[kd*64+o]
__global__ void k_pack_misc(const float* __restrict__ Wih1, const float* __restrict__ fcW,
                            u32* __restrict__ wp1, u32* __restrict__ fcT){
  int idx = blockIdx.x * 256 + threadIdx.x;
  if (idx < 131072){
    int c = idx & 255; int q = idx >> 8; int kd = q & 127; int j = q >> 7;
    int d = c >> 7, i = c & 127;
    const float* src = Wih1 + ((size_t)(j * 2 + d) * 128 + i) * 256 + kd * 2;
    wp1[idx] = pack2f(src[0], src[1]);
  } else if (idx < 131072 + 32768){
    int e = idx - 131072;
    int o = e & 63, kd = e >> 6;
    u32 v = 0;
    if (o < 61) v = pack2f(fcW[o * 1024 + kd * 2], fcW[o * 1024 + kd * 2 + 1]);
    fcT[e] = v;
  }
}

// ---------------- stage 1: per-frame biRNNs ----------------

// Layer-1 biRNN, gx fused (K=16). grid 256 = (j,d)<<5 | fblock ; block 256 (2 groups x 128 units)
__global__ __launch_bounds__(256) void k_rnn1(const float* __restrict__ batch,
    const float* __restrict__ Wih0, const float* __restrict__ Whh0,
    const float* __restrict__ bih0, const float* __restrict__ bhh0,
    u16* __restrict__ y1h){
  int bid = blockIdx.x;
  int jd = bid >> 5, fb = bid & 31;
  int j = jd >> 1, d = jd & 1;
  __shared__ float Wi[16][129];
  __shared__ float Wh[128][129];
  __shared__ float hA[8][128];
  __shared__ float hB[8][128];
  __shared__ float xf[8][3][16];
  int tid = threadIdx.x;
  for (int e = tid; e < 2048; e += 256){ int i = e >> 4, k = e & 15; Wi[k][i] = Wih0[(jd * 128 + i) * 16 + k]; }
  for (int e = tid; e < 16384; e += 256){ int i = e >> 7, k = e & 127; Wh[k][i] = Whh0[(jd * 128 + i) * 128 + k]; }
  int i = tid & 127, p = tid >> 7;
  float bias = bih0[jd * 128 + i] + bhh0[jd * 128 + i];
  __syncthreads();
  for (int g8 = 0; g8 < 8; ++g8){
    int f0 = fb * 64 + g8 * 8;
    for (int e = tid; e < 384; e += 256){
      int q = e / 48, r = e % 48, t = r >> 4, k = r & 15;
      int f = f0 + q, b = f >> 8, fr = f & 255;
      xf[q][t][k] = batch[((size_t)b * 768 + fr * 3 + t) * 64 + j * 16 + k];
    }
    __syncthreads();
    int q0 = p * 4;
    for (int tt = 0; tt < 3; ++tt){
      int ta = d ? 2 - tt : tt;
      float a0 = bias, a1 = bias, a2 = bias, a3 = bias;
      #pragma unroll
      for (int k = 0; k < 16; ++k){
        float w = Wi[k][i];
        a0 = fmaf(w, xf[q0 + 0][ta][k], a0);
        a1 = fmaf(w, xf[q0 + 1][ta][k], a1);
        a2 = fmaf(w, xf[q0 + 2][ta][k], a2);
        a3 = fmaf(w, xf[q0 + 3][ta][k], a3);
      }
      if (tt > 0){
        float (*hr)[128] = (tt == 1) ? hA : hB;
        #pragma unroll 4
        for (int k = 0; k < 128; ++k){
          float w = Wh[k][i];
          a0 = fmaf(w, hr[q0 + 0][k], a0);
          a1 = fmaf(w, hr[q0 + 1][k], a1);
          a2 = fmaf(w, hr[q0 + 2][k], a2);
          a3 = fmaf(w, hr[q0 + 3][k], a3);
        }
      }
      float h0 = ftanh(a0), h1 = ftanh(a1), hh2 = ftanh(a2), h3 = ftanh(a3);
      float (*hw)[128] = (tt & 1) ? hB : hA;
      hw[q0 + 0][i] = h0; hw[q0 + 1][i] = h1; hw[q0 + 2][i] = hh2; hw[q0 + 3][i] = h3;
      size_t obase = ((size_t)(j * 2048 + f0) * 3 + ta) * 256 + d * 128 + i;
      y1h[obase + (size_t)(q0 + 0) * 768] = f2h(h0);
      y1h[obase + (size_t)(q0 + 1) * 768] = f2h(h1);
      y1h[obase + (size_t)(q0 + 2) * 768] = f2h(hh2);
      y1h[obase + (size_t)(q0 + 3) * 768] = f2h(h3);
      __syncthreads();
    }
  }
}

// gx2 = y1 @ Wih1^T + bih1 + bhh1. grid (384 rowtiles, 4 j); block 256 (c = d*128+i)
__global__ __launch_bounds__(256) void k_gx2(const u16* __restrict__ y1h,
    const u32* __restrict__ Wp1, const float* __restrict__ bih1,
    const float* __restrict__ bhh1, u16* __restrict__ gx2h){
  int j = blockIdx.y;
  int rt0 = blockIdx.x * 16;
  __shared__ u32 yL[16][128];
  int tid = threadIdx.x;
  const u32* y1d = (const u32*)y1h;
  for (int e = tid; e < 2048; e += 256){
    int rr = e >> 7, kd = e & 127;
    yL[rr][kd] = y1d[(size_t)(j * 6144 + rt0 + rr) * 128 + kd];
  }
  __syncthreads();
  int c = tid, d = c >> 7, i = c & 127;
  float acc[16];
  #pragma unroll
  for (int rr = 0; rr < 16; ++rr) acc[rr] = 0.f;
  const u32* wp = Wp1 + (size_t)j * 128 * 256 + c;
  for (int kd = 0; kd < 128; ++kd){
    u32 w = wp[(size_t)kd * 256];
    #pragma unroll
    for (int rr = 0; rr < 16; ++rr) acc[rr] = dot2(w, yL[rr][kd], acc[rr]);
  }
  float bias = bih1[(j * 2 + d) * 128 + i] + bhh1[(j * 2 + d) * 128 + i];
  #pragma unroll
  for (int rr = 0; rr < 16; ++rr)
    gx2h[(size_t)(j * 6144 + rt0 + rr) * 256 + c] = f2h(acc[rr] + bias);
}

// Layer-2: fwd 3-step recurrence; bwd = tanh(gx2[t=2]) single step. grid 128 = j<<5|fb, block 256
__global__ __launch_bounds__(256) void k_rnn2(const u16* __restrict__ gx2h,
    const float* __restrict__ Whh1, u16* __restrict__ x0h){
  int bid = blockIdx.x;
  int j = bid >> 5, fb = bid & 31;
  __shared__ float Wh[128][129];
  __shared__ float hA[8][128];
  __shared__ float hB[8][128];
  int tid = threadIdx.x;
  for (int e = tid; e < 16384; e += 256){ int i = e >> 7, k = e & 127; Wh[k][i] = Whh1[((size_t)(j * 2) * 128 + i) * 128 + k]; }
  int i = tid & 127, p = tid >> 7, q0 = p * 4;
  __syncthreads();
  for (int g8 = 0; g8 < 8; ++g8){
    int f0 = fb * 64 + g8 * 8;
    for (int tt = 0; tt < 3; ++tt){
      float a0 = h2f(gx2h[(size_t)(j * 6144 + (f0 + q0 + 0) * 3 + tt) * 256 + i]);
      float a1 = h2f(gx2h[(size_t)(j * 6144 + (f0 + q0 + 1) * 3 + tt) * 256 + i]);
      float a2 = h2f(gx2h[(size_t)(j * 6144 + (f0 + q0 + 2) * 3 + tt) * 256 + i]);
      float a3 = h2f(gx2h[(size_t)(j * 6144 + (f0 + q0 + 3) * 3 + tt) * 256 + i]);
      if (tt > 0){
        float (*hr)[128] = (tt == 1) ? hA : hB;
        #pragma unroll 4
        for (int k = 0; k < 128; ++k){
          float w = Wh[k][i];
          a0 = fmaf(w, hr[q0 + 0][k], a0);
          a1 = fmaf(w, hr[q0 + 1][k], a1);
          a2 = fmaf(w, hr[q0 + 2][k], a2);
          a3 = fmaf(w, hr[q0 + 3][k], a3);
        }
      }
      float h0 = ftanh(a0), h1 = ftanh(a1), hh2 = ftanh(a2), h3 = ftanh(a3);
      float (*hw)[128] = (tt & 1) ? hB : hA;
      hw[q0 + 0][i] = h0; hw[q0 + 1][i] = h1; hw[q0 + 2][i] = hh2; hw[q0 + 3][i] = h3;
      if (tt == 2){
        #pragma unroll
        for (int qq = 0; qq < 4; ++qq){
          int f = f0 + q0 + qq;
          float hv = (qq == 0) ? h0 : (qq == 1) ? h1 : (qq == 2) ? hh2 : h3;
          x0h[(size_t)f * 1024 + j * 256 + i] = f2h(hv);
          float bv = ftanh(h2f(gx2h[(size_t)(j * 6144 + f * 3 + 2) * 256 + 128 + i]));
          x0h[(size_t)f * 1024 + j * 256 + 128 + i] = f2h(bv);
        }
      }
      __syncthreads();
    }
  }
}

// ---------------- GRU stack ----------------

// gx = x @ Wih^T + bih (+bhh for r,z). grid (12 ntiles, 64 = b<<3|ttile); block 256.
// 32 t-rows per WG (2x W-reuse vs r6); xL uint4 reads are wave-uniform broadcasts.
__global__ __launch_bounds__(256) void k_gru_gx(int l, const u16* __restrict__ xin,
    const u32* __restrict__ WgT, const float* __restrict__ gbih,
    const float* __restrict__ gbhh, const int* __restrict__ lengths,
    u16* __restrict__ gxh){
  int b = blockIdx.y >> 3, t0 = (blockIdx.y & 7) * 32;
  int nf = lengths[b] / 3;
  if (t0 >= nf) return;
  __shared__ __align__(16) u32 xL[32][512];
  int tid = threadIdx.x;
  const u32* xd = (const u32*)xin;
  for (int e = tid; e < 16384; e += 256){
    int rr = e >> 9, kd = e & 511;
    xL[rr][kd] = xd[(size_t)(b * 256 + t0 + rr) * 512 + kd];
  }
  __syncthreads();
  int n = blockIdx.x * 256 + tid;
  int d = (n >= 1536) ? 1 : 0;
  int g = n - d * 1536;
  float acc[32];
  #pragma unroll
  for (int rr = 0; rr < 32; ++rr) acc[rr] = 0.f;
  const u32* wp = WgT + (size_t)l * 512 * 3072 + n;
  for (int k4 = 0; k4 < 128; ++k4){
    u32 w0 = wp[(size_t)(k4 * 4 + 0) * 3072];
    u32 w1 = wp[(size_t)(k4 * 4 + 1) * 3072];
    u32 w2 = wp[(size_t)(k4 * 4 + 2) * 3072];
    u32 w3 = wp[(size_t)(k4 * 4 + 3) * 3072];
    #pragma unroll
    for (int rr = 0; rr < 32; ++rr){
      uint4 xv = *(const uint4*)&xL[rr][k4 * 4];
      acc[rr] = dot2(w0, xv.x, acc[rr]);
      acc[rr] = dot2(w1, xv.y, acc[rr]);
      acc[rr] = dot2(w2, xv.z, acc[rr]);
      acc[rr] = dot2(w3, xv.w, acc[rr]);
    }
  }
  int ld = l * 2 + d;
  float bias = gbih[ld * 1536 + g] + ((g < 1024) ? gbhh[ld * 1536 + g] : 0.f);
  #pragma unroll
  for (int rr = 0; rr < 32; ++rr)
    gxh[(size_t)((d * 8 + b) * 256 + t0 + rr) * 1536 + g] = f2h(acc[rr] + bias);
}

// GRU recurrence v7: agent-scope tagged-u64 sync (proven r3/r6) with wave-private
// poll+dot (redundant per-wave polling -> no pre-dot barrier) and parity-buffered
// single-barrier reduce. grid 256 = d<<7 | b<<4 | w ; block 256 = 4 waves:
// wave wv: K-half hh=wv>>1, rows (wv&1)? 64..95 (32 lanes) : 0..63.
// hpk u64 words per layer: [slot2][chain16][256] = {tag32 = st | 2xf16}.
__global__ __launch_bounds__(256, 1) void k_gru_rec(int l, const u16* __restrict__ gxh,
    const float* __restrict__ gbhh, const int* __restrict__ lengths,
    const u32* __restrict__ Wr, u64* __restrict__ hpk, u16* __restrict__ xout){
  int bid = blockIdx.x;
  int w = bid & 15, b = (bid >> 4) & 7, d = bid >> 7;
  int chain = d * 8 + b;
  int nf = lengths[b] / 3;
  int tid = threadIdx.x;          // 0..255
  int wv = tid >> 6, lane = tid & 63;
  int hh = wv >> 1;               // K-half this wave computes
  int act = (wv & 1) ? (lane < 32) : 1;
  int row = (wv & 1) ? (64 + (lane & 31)) : lane;   // gate-row 0..95
  int u0 = w * 32;
  __shared__ __align__(16) u32 WL[24576];   // 96 KB: [rr][256], tile-swizzled
  __shared__ __align__(16) u32 hLw[4][132]; // per-wave private h copy (128 u32 + pad)
  __shared__ float red[2][2][112];          // [parity][hh][row] partial sums
  // stage this WG's 96x512 f16 weight slice into LDS once (contiguous b128 copy)
  const float4* wsrc = (const float4*)(Wr + (size_t)((l * 2 + d) * 16 + w) * 24576);
  float4* wdst = (float4*)WL;
  for (int e = tid; e < 6144; e += 256) wdst[e] = wsrc[e];
  u64* hpl = hpk + (size_t)l * 8192;        // [slot2][chain16][256] u64 per layer
  const u16* gxb = gxh + (size_t)chain * 256 * 1536;
  float bhn = (tid < 32) ? gbhh[(l * 2 + d) * 1536 + 1024 + u0 + tid] : 0.f;
  const u32* wrow = WL + row * 256;
  int swz = row & 7;
  float hprev = 0.f;               // lane-owned unit state (wave 0 lanes 0..31), exact f32
  __syncthreads();
  for (int st = 0; st < nf; ++st){
    int t = d ? (nf - 1 - st) : st;
    // prefetch this step's gx (independent of the sync) to hide load latency
    float gr = 0.f, gz = 0.f, gn = 0.f;
    if (tid < 32){
      const u16* gxr = gxb + (size_t)t * 1536 + u0 + tid;
      gr = h2f(gxr[0]); gz = h2f(gxr[512]); gn = h2f(gxr[1024]);
    }
    // wave-private poll of this wave's K-half: 2 parallel tagged u64 loads per lane
    {
      u64* pb = hpl + (size_t)(st & 1) * 4096 + chain * 256 + hh * 128;
      u64 v0, v1; int gd = 0;
      do {
        v0 = __hip_atomic_load(&pb[lane], __ATOMIC_RELAXED, __HIP_MEMORY_SCOPE_AGENT);
        v1 = __hip_atomic_load(&pb[lane + 64], __ATOMIC_RELAXED, __HIP_MEMORY_SCOPE_AGENT);
      } while (((int)(v0 >> 32) < st || (int)(v1 >> 32) < st) && ++gd < (1 << 17));
      hLw[wv][lane] = (u32)v0;
      hLw[wv][lane + 64] = (u32)v1;
    }
    // same-wave ds_write -> ds_read ordering (no cross-wave barrier needed)
    asm volatile("s_waitcnt lgkmcnt(0)" ::: "memory");
    __builtin_amdgcn_sched_barrier(0);
    // half-K dot for this lane's row: 32 tiles (1 swizzled b128 W + 1 broadcast b128 h + 4 dot2)
    if (act){
      float a0 = 0.f, a1 = 0.f, a2 = 0.f, a3 = 0.f;
      const u32* hb = hLw[wv];
      #pragma unroll 8
      for (int tt = 0; tt < 32; ++tt){
        int t4 = hh * 32 + tt;
        uint4 hv = *(const uint4*)(hb + tt * 4);
        uint4 wvv = *(const uint4*)(wrow + (((t4 & 56) | ((t4 ^ swz) & 7)) << 2));
        a0 = dot2(wvv.x, hv.x, a0);
        a1 = dot2(wvv.y, hv.y, a1);
        a2 = dot2(wvv.z, hv.z, a2);
        a3 = dot2(wvv.w, hv.w, a3);
      }
      red[st & 1][hh][row] = (a0 + a1) + (a2 + a3);
    }
    __syncthreads();
    float hnew = 0.f;
    if (tid < 32){
      int p = st & 1;
      float dr = red[p][0][tid]       + red[p][1][tid];
      float dz = red[p][0][tid + 32]  + red[p][1][tid + 32];
      float dn = red[p][0][tid + 64]  + red[p][1][tid + 64];
      float rg = fsig(dr + gr);
      float zg = fsig(dz + gz);
      float ng = ftanh(gn + rg * (dn + bhn));
      hnew = (1.f - zg) * ng + zg * hprev;
      hprev = hnew;
    }
    // publish h_{st+1}: self-validating {tag, data} words — no fence, no flag
    float ha = __shfl(hnew, (tid & 15) * 2);
    float hb2 = __shfl(hnew, (tid & 15) * 2 + 1);
    if (tid < 16){
      u64 v = ((u64)(u32)(st + 1) << 32) | (u64)pack2f(ha, hb2);
      __hip_atomic_store(&hpl[(size_t)((st + 1) & 1) * 4096 + chain * 256 + (u0 >> 1) + tid],
                         v, __ATOMIC_RELAXED, __HIP_MEMORY_SCOPE_AGENT);
    }
    if (tid < 32)
      xout[(size_t)(b * 256 + t) * 1024 + d * 512 + u0 + tid] = f2h(hnew);
    // no trailing barrier: red is parity-double-buffered, and a wave cannot
    // reach parity p again before this WG's publish of st+1 (its poll of st+1
    // transitively requires it), which is sequenced after this gate read.
  }
}

// FC + packed gather. grid 256 = b<<5 | ttile ; block 256 = (ks = tid>>6) x (o = tid&63)
__global__ __launch_bounds__(256) void k_fc(const u16* __restrict__ x2h,
    const u32* __restrict__ fcT, const float* __restrict__ fcb,
    const int* __restrict__ lengths, float* __restrict__ out){
  int bid = blockIdx.x;
  int b = bid >> 5, t0 = (bid & 31) * 8;
  int nf = lengths[b] / 3;
  if (t0 >= nf) return;
  int off = 0;
  for (int b2 = 0; b2 < b; ++b2) off += lengths[b2] / 3;
  __shared__ u32 xL[512];
  __shared__ float redf[4][64];
  int tid = threadIdx.x;
  int o = tid & 63, ks = tid >> 6;
  const u32* xd = (const u32*)x2h;
  int tend = (t0 + 8 < nf) ? (t0 + 8) : nf;
  for (int t = t0; t < tend; ++t){
    for (int e = tid; e < 512; e += 256) xL[e] = xd[(size_t)(b * 256 + t) * 512 + e];
    __syncthreads();
    float acc = 0.f;
    const u32* fp = fcT + ks * 128 * 64 + o;
    #pragma unroll 4
    for (int kd = 0; kd < 128; ++kd)
      acc = dot2(fp[kd * 64], xL[ks * 128 + kd], acc);
    redf[ks][o] = acc;
    __syncthreads();
    if (ks == 0 && o < 61)
      out[(size_t)(off + t) * 61 + o] = redf[0][o] + redf[1][o] + redf[2][o] + redf[3][o] + fcb[o];
    __syncthreads();
  }
}

// ---------------- host ----------------

static constexpr size_t alignup(size_t x){ return (x + 255) & ~(size_t)255; }

extern "C" void kernel_launch(void* const* d_in, const int* in_sizes, int n_in,
                              void* d_out, int out_size, void* d_ws, size_t ws_size,
                              hipStream_t stream){
  const float* batch = (const float*)d_in[0];
  const int* lengths = (const int*)d_in[1];
  const float* Wih0 = (const float*)d_in[2];
  const float* Whh0 = (const float*)d_in[3];
  const float* bih0 = (const float*)d_in[4];
  const float* bhh0 = (const float*)d_in[5];
  const float* Wih1 = (const float*)d_in[6];
  const float* Whh1 = (const float*)d_in[7];
  const float* bih1 = (const float*)d_in[8];
  const float* bhh1 = (const float*)d_in[9];
  const float* gWih = (const float*)d_in[10];
  const float* gWhh = (const float*)d_in[11];
  const float* gbih = (const float*)d_in[12];
  const float* gbhh = (const float*)d_in[13];
  const float* fcW  = (const float*)d_in[14];
  const float* fcb  = (const float*)d_in[15];

  char* ws = (char*)d_ws;
  size_t off = 0;
  const size_t O_HPK  = off; off = alignup(off + (size_t)3 * 2 * 16 * 256 * 8);
  const size_t SYNC_BYTES = off;                       // zero [0, off) every launch
  const size_t O_Y1H  = off; off = alignup(off + (size_t)4 * 2048 * 3 * 256 * 2);
  const size_t O_GX2H = off; off = alignup(off + (size_t)4 * 2048 * 3 * 256 * 2);
  const size_t O_X0   = off; off = alignup(off + (size_t)8 * 256 * 1024 * 2);
  const size_t O_X1   = off; off = alignup(off + (size_t)8 * 256 * 1024 * 2);
  const size_t O_X2   = off; off = alignup(off + (size_t)8 * 256 * 1024 * 2);
  const size_t O_GXH  = off; off = alignup(off + (size_t)2 * 8 * 256 * 1536 * 2);
  const size_t O_WGT  = off; off = alignup(off + (size_t)3 * 512 * 3072 * 4);
  const size_t O_WRH  = off; off = alignup(off + (size_t)3 * 2 * 16 * 96 * 256 * 4);
  const size_t O_WP1  = off; off = alignup(off + (size_t)4 * 128 * 256 * 4);
  const size_t O_FCT  = off; off = alignup(off + (size_t)512 * 64 * 4);
  (void)ws_size; (void)in_sizes; (void)n_in; (void)out_size;

  u64* HPK  = (u64*)(ws + O_HPK);
  u16* Y1H  = (u16*)(ws + O_Y1H);
  u16* GX2H = (u16*)(ws + O_GX2H);
  u16* X0   = (u16*)(ws + O_X0);
  u16* X1   = (u16*)(ws + O_X1);
  u16* X2   = (u16*)(ws + O_X2);
  u16* GXH  = (u16*)(ws + O_GXH);
  u32* WGT  = (u32*)(ws + O_WGT);
  u32* WRH  = (u32*)(ws + O_WRH);
  u32* WP1  = (u32*)(ws + O_WP1);
  u32* FCT  = (u32*)(ws + O_FCT);

  hipMemsetAsync(ws, 0, SYNC_BYTES, stream);

  k_pack_wih <<<18432, 256, 0, stream>>>(gWih, WGT);
  k_pack_whh <<<9216, 256, 0, stream>>>(gWhh, WRH);
  k_pack_misc<<<640, 256, 0, stream>>>(Wih1, fcW, WP1, FCT);

  k_rnn1<<<256, 256, 0, stream>>>(batch, Wih0, Whh0, bih0, bhh0, Y1H);
  k_gx2 <<<dim3(384, 4), 256, 0, stream>>>(Y1H, WP1, bih1, bhh1, GX2H);
  k_rnn2<<<128, 256, 0, stream>>>(GX2H, Whh1, X0);

  u16* X[3] = { X0, X1, X2 };
  for (int l = 0; l < 3; ++l){
    u16* xin = X[l];
    u16* xout = X[(l + 1) % 3];
    k_gru_gx <<<dim3(12, 64), 256, 0, stream>>>(l, xin, WGT, gbih, gbhh, lengths, GXH);
    k_gru_rec<<<256, 256, 0, stream>>>(l, GXH, gbhh, lengths, WRH, HPK, xout);
  }
  k_fc<<<256, 256, 0, stream>>>(X[0], FCT, fcb, lengths, (float*)d_out);
}

// Round 8
// 1629.288 us; speedup vs baseline: 11.9360x; 1.3409x over previous
//
#include <hip/hip_runtime.h>

typedef unsigned int u32;
typedef unsigned short u16;
typedef unsigned long long u64;
typedef _Float16 h2v __attribute__((ext_vector_type(2)));
typedef _Float16 f16x8 __attribute__((ext_vector_type(8)));
typedef float f32x4 __attribute__((ext_vector_type(4)));

#define DEVI static __device__ __forceinline__

DEVI u32 pack2f(float a, float b){ h2v h; h[0] = (_Float16)a; h[1] = (_Float16)b; return __builtin_bit_cast(u32, h); }
DEVI u16 f2h(float a){ _Float16 h = (_Float16)a; return __builtin_bit_cast(u16, h); }
DEVI float h2f(u16 a){ return (float)__builtin_bit_cast(_Float16, a); }

#if defined(__has_builtin)
#if __has_builtin(__builtin_amdgcn_fdot2)
#define HAVE_FDOT2 1
#endif
#endif

DEVI float dot2(u32 w, u32 x, float c){
#ifdef HAVE_FDOT2
  return __builtin_amdgcn_fdot2(__builtin_bit_cast(h2v, w), __builtin_bit_cast(h2v, x), c, false);
#else
  h2v a = __builtin_bit_cast(h2v, w), b = __builtin_bit_cast(h2v, x);
  c = fmaf((float)a[0], (float)b[0], c);
  return fmaf((float)a[1], (float)b[1], c);
#endif
}

DEVI float fsig(float x){ return 1.f / (1.f + __expf(-x)); }
DEVI float ftanh(float x){
  x = fminf(12.f, fmaxf(-12.f, x));
  float e = __expf(2.f * x);
  return (e - 1.f) / (e + 1.f);
}

// ---------------- weight repack kernels ----------------

// gru_Wih (3,2,1536,1024) f32 -> MFMA B-frag-linear pack WB:
// u32 idx = ((l*32+kc)*192 + ng)*256 + lane*4 + j ; lane = kq*16+nn ;
// value = f16pair W[n = ng*16+nn][k = kc*32 + kq*8 + 2j (+1)]  (n = d*1536+g)
__global__ void k_pack_wmfma(const float* __restrict__ W, u32* __restrict__ out){
  int idx = blockIdx.x * 256 + threadIdx.x;   // 4,718,592
  int j = idx & 3;
  int lane = (idx >> 2) & 63;
  int ng = (idx >> 8) % 192;
  int r2 = (idx >> 8) / 192;
  int kc = r2 & 31, l = r2 >> 5;
  int kq = lane >> 4, nn = lane & 15;
  int n = ng * 16 + nn;
  int kd = kc * 16 + kq * 4 + j;
  int d = (n >= 1536) ? 1 : 0;
  int g = n - d * 1536;
  const float* src = W + ((size_t)((l * 2 + d) * 1536 + g)) * 1024 + kd * 2;
  out[idx] = pack2f(src[0], src[1]);
}

// gru_Whh (3,2,1536,512) f32 -> Wr[((ld*16+w)*96 + rr)*256 + kp]  LINEAR (register-resident consumer)
__global__ void k_pack_whh(const float* __restrict__ W, u32* __restrict__ out){
  int idx = blockIdx.x * 256 + threadIdx.x;   // 3*2*1536*256 = 2,359,296
  int kp = idx & 255;
  int q = idx >> 8;          // (l*2+d)*1536 + g
  int g = q % 1536;
  int ld = q / 1536;
  const float* src = W + (size_t)q * 512 + kp * 2;
  int gate = g >> 9, u = g & 511;
  int w = u >> 5, uu = u & 31;
  int rr = gate * 32 + uu;
  out[(size_t)((ld * 16 + w) * 96 + rr) * 256 + kp] = pack2f(src[0], src[1]);
}

// Wih1 -> wp1 ; fc_W -> fcT ; gru biases -> BIAS[l*3072+n] f32
__global__ void k_pack_misc(const float* __restrict__ Wih1, const float* __restrict__ fcW,
                            const float* __restrict__ gbih, const float* __restrict__ gbhh,
                            u32* __restrict__ wp1, u32* __restrict__ fcT, float* __restrict__ BIAS){
  int idx = blockIdx.x * 256 + threadIdx.x;
  if (idx < 131072){
    int c = idx & 255; int q = idx >> 8; int kd = q & 127; int j = q >> 7;
    int d = c >> 7, i = c & 127;
    const float* src = Wih1 + ((size_t)(j * 2 + d) * 128 + i) * 256 + kd * 2;
    wp1[idx] = pack2f(src[0], src[1]);
  } else if (idx < 131072 + 32768){
    int e = idx - 131072;
    int o = e & 63, kd = e >> 6;
    u32 v = 0;
    if (o < 61) v = pack2f(fcW[o * 1024 + kd * 2], fcW[o * 1024 + kd * 2 + 1]);
    fcT[e] = v;
  } else if (idx < 131072 + 32768 + 9216){
    int e = idx - 163840;
    int l = e / 3072, n = e % 3072;
    int d = (n >= 1536) ? 1 : 0;
    int g = n - d * 1536;
    int ld = l * 2 + d;
    BIAS[e] = gbih[ld * 1536 + g] + ((g < 1024) ? gbhh[ld * 1536 + g] : 0.f);
  }
}

// ---------------- stage 1: per-frame biRNNs ----------------

// Layer-1 biRNN, gx fused (K=16). grid 256 = (j,d)<<5 | fblock ; block 256 (2 groups x 128 units)
__global__ __launch_bounds__(256) void k_rnn1(const float* __restrict__ batch,
    const float* __restrict__ Wih0, const float* __restrict__ Whh0,
    const float* __restrict__ bih0, const float* __restrict__ bhh0,
    u16* __restrict__ y1h){
  int bid = blockIdx.x;
  int jd = bid >> 5, fb = bid & 31;
  int j = jd >> 1, d = jd & 1;
  __shared__ float Wi[16][129];
  __shared__ float Wh[128][129];
  __shared__ float hA[8][128];
  __shared__ float hB[8][128];
  __shared__ float xf[8][3][16];
  int tid = threadIdx.x;
  for (int e = tid; e < 2048; e += 256){ int i = e >> 4, k = e & 15; Wi[k][i] = Wih0[(jd * 128 + i) * 16 + k]; }
  for (int e = tid; e < 16384; e += 256){ int i = e >> 7, k = e & 127; Wh[k][i] = Whh0[(jd * 128 + i) * 128 + k]; }
  int i = tid & 127, p = tid >> 7;
  float bias = bih0[jd * 128 + i] + bhh0[jd * 128 + i];
  __syncthreads();
  for (int g8 = 0; g8 < 8; ++g8){
    int f0 = fb * 64 + g8 * 8;
    for (int e = tid; e < 384; e += 256){
      int q = e / 48, r = e % 48, t = r >> 4, k = r & 15;
      int f = f0 + q, b = f >> 8, fr = f & 255;
      xf[q][t][k] = batch[((size_t)b * 768 + fr * 3 + t) * 64 + j * 16 + k];
    }
    __syncthreads();
    int q0 = p * 4;
    for (int tt = 0; tt < 3; ++tt){
      int ta = d ? 2 - tt : tt;
      float a0 = bias, a1 = bias, a2 = bias, a3 = bias;
      #pragma unroll
      for (int k = 0; k < 16; ++k){
        float w = Wi[k][i];
        a0 = fmaf(w, xf[q0 + 0][ta][k], a0);
        a1 = fmaf(w, xf[q0 + 1][ta][k], a1);
        a2 = fmaf(w, xf[q0 + 2][ta][k], a2);
        a3 = fmaf(w, xf[q0 + 3][ta][k], a3);
      }
      if (tt > 0){
        float (*hr)[128] = (tt == 1) ? hA : hB;
        #pragma unroll 4
        for (int k = 0; k < 128; ++k){
          float w = Wh[k][i];
          a0 = fmaf(w, hr[q0 + 0][k], a0);
          a1 = fmaf(w, hr[q0 + 1][k], a1);
          a2 = fmaf(w, hr[q0 + 2][k], a2);
          a3 = fmaf(w, hr[q0 + 3][k], a3);
        }
      }
      float h0 = ftanh(a0), h1 = ftanh(a1), hh2 = ftanh(a2), h3 = ftanh(a3);
      float (*hw)[128] = (tt & 1) ? hB : hA;
      hw[q0 + 0][i] = h0; hw[q0 + 1][i] = h1; hw[q0 + 2][i] = hh2; hw[q0 + 3][i] = h3;
      size_t obase = ((size_t)(j * 2048 + f0) * 3 + ta) * 256 + d * 128 + i;
      y1h[obase + (size_t)(q0 + 0) * 768] = f2h(h0);
      y1h[obase + (size_t)(q0 + 1) * 768] = f2h(h1);
      y1h[obase + (size_t)(q0 + 2) * 768] = f2h(hh2);
      y1h[obase + (size_t)(q0 + 3) * 768] = f2h(h3);
      __syncthreads();
    }
  }
}

// gx2 = y1 @ Wih1^T + bih1 + bhh1. grid (384 rowtiles, 4 j); block 256 (c = d*128+i)
__global__ __launch_bounds__(256) void k_gx2(const u16* __restrict__ y1h,
    const u32* __restrict__ Wp1, const float* __restrict__ bih1,
    const float* __restrict__ bhh1, u16* __restrict__ gx2h){
  int j = blockIdx.y;
  int rt0 = blockIdx.x * 16;
  __shared__ u32 yL[16][128];
  int tid = threadIdx.x;
  const u32* y1d = (const u32*)y1h;
  for (int e = tid; e < 2048; e += 256){
    int rr = e >> 7, kd = e & 127;
    yL[rr][kd] = y1d[(size_t)(j * 6144 + rt0 + rr) * 128 + kd];
  }
  __syncthreads();
  int c = tid, d = c >> 7, i = c & 127;
  float acc[16];
  #pragma unroll
  for (int rr = 0; rr < 16; ++rr) acc[rr] = 0.f;
  const u32* wp = Wp1 + (size_t)j * 128 * 256 + c;
  for (int kd = 0; kd < 128; ++kd){
    u32 w = wp[(size_t)kd * 256];
    #pragma unroll
    for (int rr = 0; rr < 16; ++rr) acc[rr] = dot2(w, yL[rr][kd], acc[rr]);
  }
  float bias = bih1[(j * 2 + d) * 128 + i] + bhh1[(j * 2 + d) * 128 + i];
  #pragma unroll
  for (int rr = 0; rr < 16; ++rr)
    gx2h[(size_t)(j * 6144 + rt0 + rr) * 256 + c] = f2h(acc[rr] + bias);
}

// Layer-2: fwd 3-step recurrence; bwd = tanh(gx2[t=2]) single step. grid 128 = j<<5|fb, block 256
__global__ __launch_bounds__(256) void k_rnn2(const u16* __restrict__ gx2h,
    const float* __restrict__ Whh1, u16* __restrict__ x0h){
  int bid = blockIdx.x;
  int j = bid >> 5, fb = bid & 31;
  __shared__ float Wh[128][129];
  __shared__ float hA[8][128];
  __shared__ float hB[8][128];
  int tid = threadIdx.x;
  for (int e = tid; e < 16384; e += 256){ int i = e >> 7, k = e & 127; Wh[k][i] = Whh1[((size_t)(j * 2) * 128 + i) * 128 + k]; }
  int i = tid & 127, p = tid >> 7, q0 = p * 4;
  __syncthreads();
  for (int g8 = 0; g8 < 8; ++g8){
    int f0 = fb * 64 + g8 * 8;
    for (int tt = 0; tt < 3; ++tt){
      float a0 = h2f(gx2h[(size_t)(j * 6144 + (f0 + q0 + 0) * 3 + tt) * 256 + i]);
      float a1 = h2f(gx2h[(size_t)(j * 6144 + (f0 + q0 + 1) * 3 + tt) * 256 + i]);
      float a2 = h2f(gx2h[(size_t)(j * 6144 + (f0 + q0 + 2) * 3 + tt) * 256 + i]);
      float a3 = h2f(gx2h[(size_t)(j * 6144 + (f0 + q0 + 3) * 3 + tt) * 256 + i]);
      if (tt > 0){
        float (*hr)[128] = (tt == 1) ? hA : hB;
        #pragma unroll 4
        for (int k = 0; k < 128; ++k){
          float w = Wh[k][i];
          a0 = fmaf(w, hr[q0 + 0][k], a0);
          a1 = fmaf(w, hr[q0 + 1][k], a1);
          a2 = fmaf(w, hr[q0 + 2][k], a2);
          a3 = fmaf(w, hr[q0 + 3][k], a3);
        }
      }
      float h0 = ftanh(a0), h1 = ftanh(a1), hh2 = ftanh(a2), h3 = ftanh(a3);
      float (*hw)[128] = (tt & 1) ? hB : hA;
      hw[q0 + 0][i] = h0; hw[q0 + 1][i] = h1; hw[q0 + 2][i] = hh2; hw[q0 + 3][i] = h3;
      if (tt == 2){
        #pragma unroll
        for (int qq = 0; qq < 4; ++qq){
          int f = f0 + q0 + qq;
          float hv = (qq == 0) ? h0 : (qq == 1) ? h1 : (qq == 2) ? hh2 : h3;
          x0h[(size_t)f * 1024 + j * 256 + i] = f2h(hv);
          float bv = ftanh(h2f(gx2h[(size_t)(j * 6144 + f * 3 + 2) * 256 + 128 + i]));
          x0h[(size_t)f * 1024 + j * 256 + 128 + i] = f2h(bv);
        }
      }
      __syncthreads();
    }
  }
}

// ---------------- GRU stack ----------------

// gx via MFMA 16x16x32_f16. grid (24 nblocks, 64 = b<<3|ttile); block 256 = 4 waves.
// Block tile M=32 (t-rows) x N=128 (cols of 3072). Wave: M-half (wv&1) x N-quarter (wv>>1).
__global__ __launch_bounds__(256) void k_gru_gxm(int l, const u16* __restrict__ xin,
    const u32* __restrict__ WB, const float* __restrict__ BIAS,
    const int* __restrict__ lengths, u16* __restrict__ gxh){
  int b = blockIdx.y >> 3, t0 = (blockIdx.y & 7) * 32;
  int nf = lengths[b] / 3;
  if (t0 >= nf) return;
  __shared__ __align__(16) u32 xL[32 * 516];   // rows padded to 516 u32 (odd 16B stride)
  int tid = threadIdx.x;
  const uint4* xd = (const uint4*)xin;
  for (int e = tid; e < 4096; e += 256){
    int row = e >> 7, kd4 = e & 127;
    *(uint4*)(xL + row * 516 + kd4 * 4) = xd[(size_t)(b * 256 + t0 + row) * 128 + kd4];
  }
  __syncthreads();
  int wv = tid >> 6, lane = tid & 63;
  int m0w = (wv & 1) * 16;
  int ng0 = blockIdx.x * 8 + (wv >> 1) * 4;    // 4 groups of 16 cols per wave
  const u32* aL = xL + (m0w + (lane & 15)) * 516 + (lane >> 4) * 4;
  const uint4* wb4 = (const uint4*)WB;
  f32x4 acc0 = {0.f,0.f,0.f,0.f}, acc1 = acc0, acc2 = acc0, acc3 = acc0;
  for (int kc = 0; kc < 32; ++kc){
    uint4 av = *(const uint4*)(aL + kc * 16);
    f16x8 af = __builtin_bit_cast(f16x8, av);
    const uint4* wp = wb4 + ((size_t)(l * 32 + kc) * 192 + ng0) * 64 + lane;
    uint4 b0 = wp[0], b1 = wp[64], b2 = wp[128], b3 = wp[192];
    acc0 = __builtin_amdgcn_mfma_f32_16x16x32_f16(af, __builtin_bit_cast(f16x8, b0), acc0, 0, 0, 0);
    acc1 = __builtin_amdgcn_mfma_f32_16x16x32_f16(af, __builtin_bit_cast(f16x8, b1), acc1, 0, 0, 0);
    acc2 = __builtin_amdgcn_mfma_f32_16x16x32_f16(af, __builtin_bit_cast(f16x8, b2), acc2, 0, 0, 0);
    acc3 = __builtin_amdgcn_mfma_f32_16x16x32_f16(af, __builtin_bit_cast(f16x8, b3), acc3, 0, 0, 0);
  }
  // epilogue: D col = lane&15, row = (lane>>4)*4 + i  [m89]
  int mrow = t0 + m0w + (lane >> 4) * 4;
  #pragma unroll
  for (int sub = 0; sub < 4; ++sub){
    f32x4 ac = (sub == 0) ? acc0 : (sub == 1) ? acc1 : (sub == 2) ? acc2 : acc3;
    int n = (ng0 + sub) * 16 + (lane & 15);
    int d = (n >= 1536) ? 1 : 0;
    int g = n - d * 1536;
    float bias = BIAS[l * 3072 + n];
    u16* op = gxh + (size_t)((d * 8 + b) * 256 + mrow) * 1536 + g;
    #pragma unroll
    for (int i = 0; i < 4; ++i) op[(size_t)i * 1536] = f2h(ac[i] + bias);
  }
}

// GRU recurrence v8: round-7 sync structure (agent-scope tagged-u64, wave-private poll,
// parity reduce) with Whh held in REGISTERS (128 u32/lane) — no LDS W stream.
// grid 256 = d<<7 | b<<4 | w ; block 256 = 4 waves: wave wv: K-half hh=wv>>1,
// rows (wv&1)? 64..95 (32 lanes) : 0..63.
__global__ __launch_bounds__(256, 1) void k_gru_rec(int l, const u16* __restrict__ gxh,
    const float* __restrict__ gbhh, const int* __restrict__ lengths,
    const u32* __restrict__ Wr, u64* __restrict__ hpk, u16* __restrict__ xout){
  int bid = blockIdx.x;
  int w = bid & 15, b = (bid >> 4) & 7, d = bid >> 7;
  int chain = d * 8 + b;
  int nf = lengths[b] / 3;
  int tid = threadIdx.x;          // 0..255
  int wv = tid >> 6, lane = tid & 63;
  int hh = wv >> 1;               // K-half this wave computes
  int act = (wv & 1) ? (lane < 32) : 1;
  int row = (wv & 1) ? (64 + (lane & 31)) : lane;   // gate-row 0..95
  int u0 = w * 32;
  __shared__ __align__(16) u32 hLw[4][132]; // per-wave private h copy (128 u32 + pad)
  __shared__ float red[2][2][112];          // [parity][hh][row] partial sums
  // load this lane's (row, K-half) weight slice into registers: 32 uint4 = 128 u32
  const uint4* wsrc = (const uint4*)(Wr + (((size_t)((l * 2 + d) * 16 + w) * 96 + row) * 256 + hh * 128));
  uint4 wreg[32];
  #pragma unroll
  for (int tt = 0; tt < 32; ++tt) wreg[tt] = wsrc[tt];
  u64* hpl = hpk + (size_t)l * 8192;        // [slot2][chain16][256] u64 per layer
  const u16* gxb = gxh + (size_t)chain * 256 * 1536;
  float bhn = (tid < 32) ? gbhh[(l * 2 + d) * 1536 + 1024 + u0 + tid] : 0.f;
  float hprev = 0.f;               // lane-owned unit state (wave 0 lanes 0..31), exact f32
  __syncthreads();
  for (int st = 0; st < nf; ++st){
    int t = d ? (nf - 1 - st) : st;
    // prefetch this step's gx (independent of the sync) to hide load latency
    float gr = 0.f, gz = 0.f, gn = 0.f;
    if (tid < 32){
      const u16* gxr = gxb + (size_t)t * 1536 + u0 + tid;
      gr = h2f(gxr[0]); gz = h2f(gxr[512]); gn = h2f(gxr[1024]);
    }
    // wave-private poll of this wave's K-half: 2 parallel tagged u64 loads per lane
    {
      u64* pb = hpl + (size_t)(st & 1) * 4096 + chain * 256 + hh * 128;
      u64 v0, v1; int gd = 0;
      do {
        v0 = __hip_atomic_load(&pb[lane], __ATOMIC_RELAXED, __HIP_MEMORY_SCOPE_AGENT);
        v1 = __hip_atomic_load(&pb[lane + 64], __ATOMIC_RELAXED, __HIP_MEMORY_SCOPE_AGENT);
      } while (((int)(v0 >> 32) < st || (int)(v1 >> 32) < st) && ++gd < (1 << 17));
      hLw[wv][lane] = (u32)v0;
      hLw[wv][lane + 64] = (u32)v1;
    }
    // same-wave ds_write -> ds_read ordering (no cross-wave barrier needed)
    asm volatile("s_waitcnt lgkmcnt(0)" ::: "memory");
    __builtin_amdgcn_sched_barrier(0);
    // half-K dot: 32 tiles x (1 broadcast b128 h read + 4 register-operand dot2)
    if (act){
      float a0 = 0.f, a1 = 0.f, a2 = 0.f, a3 = 0.f;
      const u32* hb = hLw[wv];
      #pragma unroll
      for (int tt = 0; tt < 32; ++tt){
        uint4 hv = *(const uint4*)(hb + tt * 4);
        a0 = dot2(wreg[tt].x, hv.x, a0);
        a1 = dot2(wreg[tt].y, hv.y, a1);
        a2 = dot2(wreg[tt].z, hv.z, a2);
        a3 = dot2(wreg[tt].w, hv.w, a3);
      }
      red[st & 1][hh][row] = (a0 + a1) + (a2 + a3);
    }
    __syncthreads();
    float hnew = 0.f;
    if (tid < 32){
      int p = st & 1;
      float dr = red[p][0][tid]       + red[p][1][tid];
      float dz = red[p][0][tid + 32]  + red[p][1][tid + 32];
      float dn = red[p][0][tid + 64]  + red[p][1][tid + 64];
      float rg = fsig(dr + gr);
      float zg = fsig(dz + gz);
      float ng = ftanh(gn + rg * (dn + bhn));
      hnew = (1.f - zg) * ng + zg * hprev;
      hprev = hnew;
    }
    // publish h_{st+1}: self-validating {tag, data} words — no fence, no flag
    float ha = __shfl(hnew, (tid & 15) * 2);
    float hb2 = __shfl(hnew, (tid & 15) * 2 + 1);
    if (tid < 16){
      u64 v = ((u64)(u32)(st + 1) << 32) | (u64)pack2f(ha, hb2);
      __hip_atomic_store(&hpl[(size_t)((st + 1) & 1) * 4096 + chain * 256 + (u0 >> 1) + tid],
                         v, __ATOMIC_RELAXED, __HIP_MEMORY_SCOPE_AGENT);
    }
    if (tid < 32)
      xout[(size_t)(b * 256 + t) * 1024 + d * 512 + u0 + tid] = f2h(hnew);
    // no trailing barrier: red is parity-double-buffered (see r7 proof).
  }
}

// FC + packed gather. grid 256 = b<<5 | ttile ; block 256 = (ks = tid>>6) x (o = tid&63)
__global__ __launch_bounds__(256) void k_fc(const u16* __restrict__ x2h,
    const u32* __restrict__ fcT, const float* __restrict__ fcb,
    const int* __restrict__ lengths, float* __restrict__ out){
  int bid = blockIdx.x;
  int b = bid >> 5, t0 = (bid & 31) * 8;
  int nf = lengths[b] / 3;
  if (t0 >= nf) return;
  int off = 0;
  for (int b2 = 0; b2 < b; ++b2) off += lengths[b2] / 3;
  __shared__ u32 xL[512];
  __shared__ float redf[4][64];
  int tid = threadIdx.x;
  int o = tid & 63, ks = tid >> 6;
  const u32* xd = (const u32*)x2h;
  int tend = (t0 + 8 < nf) ? (t0 + 8) : nf;
  for (int t = t0; t < tend; ++t){
    for (int e = tid; e < 512; e += 256) xL[e] = xd[(size_t)(b * 256 + t) * 512 + e];
    __syncthreads();
    float acc = 0.f;
    const u32* fp = fcT + ks * 128 * 64 + o;
    #pragma unroll 4
    for (int kd = 0; kd < 128; ++kd)
      acc = dot2(fp[kd * 64], xL[ks * 128 + kd], acc);
    redf[ks][o] = acc;
    __syncthreads();
    if (ks == 0 && o < 61)
      out[(size_t)(off + t) * 61 + o] = redf[0][o] + redf[1][o] + redf[2][o] + redf[3][o] + fcb[o];
    __syncthreads();
  }
}

// ---------------- host ----------------

static constexpr size_t alignup(size_t x){ return (x + 255) & ~(size_t)255; }

extern "C" void kernel_launch(void* const* d_in, const int* in_sizes, int n_in,
                              void* d_out, int out_size, void* d_ws, size_t ws_size,
                              hipStream_t stream){
  const float* batch = (const float*)d_in[0];
  const int* lengths = (const int*)d_in[1];
  const float* Wih0 = (const float*)d_in[2];
  const float* Whh0 = (const float*)d_in[3];
  const float* bih0 = (const float*)d_in[4];
  const float* bhh0 = (const float*)d_in[5];
  const float* Wih1 = (const float*)d_in[6];
  const float* Whh1 = (const float*)d_in[7];
  const float* bih1 = (const float*)d_in[8];
  const float* bhh1 = (const float*)d_in[9];
  const float* gWih = (const float*)d_in[10];
  const float* gWhh = (const float*)d_in[11];
  const float* gbih = (const float*)d_in[12];
  const float* gbhh = (const float*)d_in[13];
  const float* fcW  = (const float*)d_in[14];
  const float* fcb  = (const float*)d_in[15];

  char* ws = (char*)d_ws;
  size_t off = 0;
  const size_t O_HPK  = off; off = alignup(off + (size_t)3 * 2 * 16 * 256 * 8);
  const size_t SYNC_BYTES = off;                       // zero [0, off) every launch
  const size_t O_Y1H  = off; off = alignup(off + (size_t)4 * 2048 * 3 * 256 * 2);
  const size_t O_GX2H = off; off = alignup(off + (size_t)4 * 2048 * 3 * 256 * 2);
  const size_t O_X0   = off; off = alignup(off + (size_t)8 * 256 * 1024 * 2);
  const size_t O_X1   = off; off = alignup(off + (size_t)8 * 256 * 1024 * 2);
  const size_t O_X2   = off; off = alignup(off + (size_t)8 * 256 * 1024 * 2);
  const size_t O_GXH  = off; off = alignup(off + (size_t)2 * 8 * 256 * 1536 * 2);
  const size_t O_WBM  = off; off = alignup(off + (size_t)3 * 512 * 3072 * 4);
  const size_t O_WRH  = off; off = alignup(off + (size_t)3 * 2 * 16 * 96 * 256 * 4);
  const size_t O_WP1  = off; off = alignup(off + (size_t)4 * 128 * 256 * 4);
  const size_t O_FCT  = off; off = alignup(off + (size_t)512 * 64 * 4);
  const size_t O_BIAS = off; off = alignup(off + (size_t)3 * 3072 * 4);
  (void)ws_size; (void)in_sizes; (void)n_in; (void)out_size;

  u64* HPK  = (u64*)(ws + O_HPK);
  u16* Y1H  = (u16*)(ws + O_Y1H);
  u16* GX2H = (u16*)(ws + O_GX2H);
  u16* X0   = (u16*)(ws + O_X0);
  u16* X1   = (u16*)(ws + O_X1);
  u16* X2   = (u16*)(ws + O_X2);
  u16* GXH  = (u16*)(ws + O_GXH);
  u32* WBM  = (u32*)(ws + O_WBM);
  u32* WRH  = (u32*)(ws + O_WRH);
  u32* WP1  = (u32*)(ws + O_WP1);
  u32* FCT  = (u32*)(ws + O_FCT);
  float* BIAS = (float*)(ws + O_BIAS);

  hipMemsetAsync(ws, 0, SYNC_BYTES, stream);

  k_pack_wmfma<<<18432, 256, 0, stream>>>(gWih, WBM);
  k_pack_whh  <<<9216, 256, 0, stream>>>(gWhh, WRH);
  k_pack_misc <<<676, 256, 0, stream>>>(Wih1, fcW, gbih, gbhh, WP1, FCT, BIAS);

  k_rnn1<<<256, 256, 0, stream>>>(batch, Wih0, Whh0, bih0, bhh0, Y1H);
  k_gx2 <<<dim3(384, 4), 256, 0, stream>>>(Y1H, WP1, bih1, bhh1, GX2H);
  k_rnn2<<<128, 256, 0, stream>>>(GX2H, Whh1, X0);

  u16* X[3] = { X0, X1, X2 };
  for (int l = 0; l < 3; ++l){
    u16* xin = X[l];
    u16* xout = X[(l + 1) % 3];
    k_gru_gxm<<<dim3(24, 64), 256, 0, stream>>>(l, xin, WBM, BIAS, lengths, GXH);
    k_gru_rec<<<256, 256, 0, stream>>>(l, GXH, gbhh, lengths, WRH, HPK, xout);
  }
  k_fc<<<256, 256, 0, stream>>>(X[0], FCT, fcb, lengths, (float*)d_out);
}